// Round 10
// baseline (609.210 us; speedup 1.0000x reference)
//
#include <hip/hip_runtime.h>
#include <hip/hip_bf16.h>

// PPI GAT, 3 layers. N=50000, E=800000 (+N self loops), avg degree ~17.
// R15: R14 won (613->598; reg-dbuf + XCD swizzle). agg4 at 93% of the
// ~3.6TB/s random-gather ceiling, FETCH at 235MB floor -> done. This round:
// full-K LDS GEMM. K is tiny (128/256) so BOTH tiles fit in LDS (69/135KB
// <= 160KB/CU): stage everything once with 16-32 uint4 loads in flight,
// ONE barrier, then 64-128 back-to-back MFMAs (zero inner barriers).
// 1 block/CU at K=256 is fine - MFMA-dense streams don't need occupancy.
// skinny64 keeps R14's reg-dbuf (K=1536 doesn't fit).

#define NODES 50000
#define EDGES 800000
#define MPAD  50048            // ceil(N/128)*128
#define C0    25088            // layer-3 chunk-0 rows
#define C1    24912            // layer-3 chunk-1 rows

typedef unsigned short u16;
typedef __attribute__((ext_vector_type(8))) short bf16x8;
typedef __attribute__((ext_vector_type(4))) float f32x4;

__device__ __forceinline__ float bf16f(u16 r) {
    return __uint_as_float(((unsigned)r) << 16);
}
__device__ __forceinline__ u16 f2b(float v) {
    __hip_bfloat16 b = __float2bfloat16(v);
    return *(u16*)&b;
}
__device__ __forceinline__ float blo(unsigned d) { return __uint_as_float(d << 16); }
__device__ __forceinline__ float bhi(unsigned d) { return __uint_as_float(d & 0xffff0000u); }

// ---------------- CSR build ----------------

__global__ void fill_ones_kernel(int* __restrict__ deg, int n) {
    int i = blockIdx.x * blockDim.x + threadIdx.x;
    if (i < n) deg[i] = 1;  // self-loop
}

__global__ void hist_kernel(const int* __restrict__ dst, int* __restrict__ deg, int E) {
    int e = blockIdx.x * blockDim.x + threadIdx.x;
    if (e < E) atomicAdd(&deg[dst[e]], 1);
}

__global__ void deg_bsum_kernel(const int* __restrict__ deg, int* __restrict__ bsum, int n) {
    int tid = threadIdx.x, lane = tid & 63, wid = tid >> 6;
    int i = blockIdx.x * 256 + tid;
    int v = (i < n) ? deg[i] : 0;
    #pragma unroll
    for (int ofs = 32; ofs > 0; ofs >>= 1) v += __shfl_down(v, ofs);
    __shared__ int sp[4];
    if (lane == 0) sp[wid] = v;
    __syncthreads();
    if (tid == 0) bsum[blockIdx.x] = sp[0] + sp[1] + sp[2] + sp[3];
}

__global__ void bsum_scan_kernel(int* __restrict__ bsum, int* __restrict__ row_ptr,
                                 int nb, int n) {
    int tid = threadIdx.x, lane = tid & 63, wid = tid >> 6;
    int v = (tid < nb) ? bsum[tid] : 0;
    int incl = v;
    #pragma unroll
    for (int ofs = 1; ofs < 64; ofs <<= 1) {
        int t = __shfl_up(incl, ofs);
        if (lane >= ofs) incl += t;
    }
    __shared__ int sp[4];
    if (lane == 63) sp[wid] = incl;
    __syncthreads();
    int add = 0;
    for (int k = 0; k < wid; k++) add += sp[k];
    int excl = incl - v + add;
    if (tid < nb) bsum[tid] = excl;
    if (tid == nb - 1) row_ptr[n] = excl + v;
}

__global__ void deg_scan_kernel(const int* __restrict__ deg, const int* __restrict__ bofs,
                                int* __restrict__ row_ptr, int* __restrict__ cursor, int n) {
    int tid = threadIdx.x, lane = tid & 63, wid = tid >> 6;
    int i = blockIdx.x * 256 + tid;
    int v = (i < n) ? deg[i] : 0;
    int incl = v;
    #pragma unroll
    for (int ofs = 1; ofs < 64; ofs <<= 1) {
        int t = __shfl_up(incl, ofs);
        if (lane >= ofs) incl += t;
    }
    __shared__ int sp[4];
    if (lane == 63) sp[wid] = incl;
    __syncthreads();
    int add = bofs[blockIdx.x];
    for (int k = 0; k < wid; k++) add += sp[k];
    int excl = incl - v + add;
    if (i < n) { row_ptr[i] = excl; cursor[i] = excl; }
}

__global__ void scatter_kernel(const int* __restrict__ src, const int* __restrict__ dst,
                               int E, int n, int* __restrict__ cursor, int* __restrict__ csr_src) {
    int e = blockIdx.x * blockDim.x + threadIdx.x;
    if (e < E) {
        int d = dst[e];
        int p = atomicAdd(&cursor[d], 1);
        csr_src[p] = src[e];
    } else if (e < E + n) {
        int i = e - E;
        int p = atomicAdd(&cursor[i], 1);
        csr_src[p] = i;  // self-loop
    }
}

// ---------------- prep: all weight converts + q-vectors, one launch ----------------

__global__ void prep_weights(
    const float* __restrict__ W1, const float* __restrict__ W2,
    const float* __restrict__ Wres2, const float* __restrict__ W3,
    const float* __restrict__ a1s, const float* __restrict__ a1d,
    const float* __restrict__ a2s, const float* __restrict__ a2d,
    const float* __restrict__ a3s, const float* __restrict__ a3d,
    u16* __restrict__ WT1, u16* __restrict__ WT2, u16* __restrict__ W3sT,
    float* __restrict__ q1t, float* __restrict__ q2t, float* __restrict__ cm) {
    int idx = blockIdx.x * 256 + threadIdx.x;
    if (idx < 32768) {                        // WT1
        int n = idx >> 7, k = idx & 127;
        WT1[idx] = f2b(W1[(size_t)k * 256 + n]);
    } else if ((idx -= 32768) < 131072) {     // WT2 = [W2 | Wres2]
        int n = idx >> 8, k = idx & 255;
        float v = (n < 256) ? W2[(size_t)k * 256 + n] : Wres2[(size_t)k * 256 + (n - 256)];
        WT2[idx] = f2b(v);
    } else if ((idx -= 131072) < 196608) {    // W3sT
        int n = idx / 1536, q = idx % 1536;
        int h = q >> 8, k = q & 255;
        W3sT[idx] = f2b((n < 121) ? W3[(size_t)k * 726 + h * 121 + n] : 0.f);
    } else if ((idx -= 196608) < 1024) {      // q1t
        int h = idx >> 7, k = idx & 127;
        int hh = h & 3;
        const float* a = (h < 4) ? a1s : a1d;
        float v = 0.f;
        for (int c = 0; c < 64; c++) v += W1[(size_t)k * 256 + hh * 64 + c] * a[hh * 64 + c];
        q1t[idx] = v;
    } else if ((idx -= 1024) < 2048) {        // q2t [8][256]
        int h = idx >> 8, k = idx & 255;
        int hh = h & 3;
        const float* a = (h < 4) ? a2s : a2d;
        float v = 0.f;
        for (int c = 0; c < 64; c++) v += W2[(size_t)k * 256 + hh * 64 + c] * a[hh * 64 + c];
        q2t[idx] = v;
    } else if ((idx -= 2048) < 3072) {        // cm [12][256]
        int o = idx >> 8, k = idx & 255;
        int h = (o < 6) ? o : o - 6;
        const float* a = (o < 6) ? a3s : a3d;
        float v = 0.f;
        for (int c = 0; c < 121; c++) v += W3[(size_t)k * 726 + h * 121 + c] * a[h * 121 + c];
        cm[idx] = v;
    }
}
#define PREP_TOTAL (32768 + 131072 + 196608 + 1024 + 2048 + 3072)

// ---------------- convx + layer-1 logits: wave per node ----------------

__global__ __launch_bounds__(256) void convx_al1(
    const float* __restrict__ x, const float* __restrict__ q1t,
    u16* __restrict__ A2a, float* __restrict__ alA, int n) {
    int wid = threadIdx.x >> 6, lane = threadIdx.x & 63;
    int i = blockIdx.x * 4 + wid;
    if (i >= n) return;
    float2 xv = *(const float2*)(x + (size_t)i * 128 + lane * 2);
    ushort2 o;
    o.x = f2b(xv.x); o.y = f2b(xv.y);
    *(ushort2*)(A2a + (size_t)i * 128 + lane * 2) = o;
    float p[8];
    #pragma unroll
    for (int h = 0; h < 8; h++) {
        float2 q = *(const float2*)(q1t + h * 128 + lane * 2);
        p[h] = xv.x * q.x + xv.y * q.y;
    }
    #pragma unroll
    for (int ofs = 1; ofs <= 32; ofs <<= 1) {
        #pragma unroll
        for (int h = 0; h < 8; h++) p[h] += __shfl_xor(p[h], ofs);
    }
    if (lane == 0) {
        *(float4*)(alA + (size_t)i * 8)     = make_float4(p[0], p[1], p[2], p[3]);
        *(float4*)(alA + (size_t)i * 8 + 4) = make_float4(p[4], p[5], p[6], p[7]);
    }
}

// ---------------- full-K LDS MFMA GEMM: C = A @ B^T, bf16 out, col split ----------------
// R15: the ENTIRE K fits in LDS (K2=128: 69KB; K2=256: 135KB <= 160KB/CU).
// Stage once (ITER uint4 loads/thread, all in flight), one barrier, then
// K2/32 * 16 MFMAs back-to-back with zero inner barriers. XCD-swizzled 1D
// grid (x=b&7 -> XCD): per-XCD consecutive blocks = all NT col-tiles of one
// A row-panel -> panel fetched into exactly one L2.

template <int K2, int NT>
__global__ __launch_bounds__(256) void gemm_fullk(
    const u16* __restrict__ A, const u16* __restrict__ B,
    u16* __restrict__ Cb, u16* __restrict__ Cb2,
    int M, int ldc, int split, int nrt) {
    constexpr int KP = K2 + 8;              // +8 u16 pad: lm-lanes spread 8 banks
    __shared__ __align__(16) u16 As[128][KP];
    __shared__ __align__(16) u16 Bs[128][KP];
    int b = blockIdx.x;
    int xcd = b & 7, q = b >> 3;
    int ct = q % NT, rb = q / NT;
    int rt = rb * 8 + xcd;
    if (rt >= nrt) return;
    int bm = rt * 128, bn = ct * 128;

    int tid = threadIdx.x;
    int lane = tid & 63, wv = tid >> 6;
    int quad = lane >> 4, lm = lane & 15;
    int wm = (wv & 1) * 64, wn = (wv >> 1) * 64;

    // stage both tiles fully
    constexpr int SEGROW = K2 / 8;          // uint4 segments per row
    constexpr int ITER = 128 * SEGROW / 256;
    #pragma unroll
    for (int it = 0; it < ITER; ++it) {
        int s = tid + it * 256;
        int row = s / SEGROW, c8 = (s % SEGROW) * 8;
        *(uint4*)&As[row][c8] = *(const uint4*)(A + (size_t)(bm + row) * K2 + c8);
        *(uint4*)&Bs[row][c8] = *(const uint4*)(B + (size_t)(bn + row) * K2 + c8);
    }
    __syncthreads();

    f32x4 zero = {0.f, 0.f, 0.f, 0.f};
    f32x4 acc[4][4];
    #pragma unroll
    for (int i = 0; i < 4; i++)
        #pragma unroll
        for (int j = 0; j < 4; j++) acc[i][j] = zero;

    #pragma unroll
    for (int k0 = 0; k0 < K2; k0 += 32) {
        bf16x8 af[4], bfr[4];
        #pragma unroll
        for (int i = 0; i < 4; i++) af[i] = *(const bf16x8*)&As[wm + i * 16 + lm][k0 + quad * 8];
        #pragma unroll
        for (int j = 0; j < 4; j++) bfr[j] = *(const bf16x8*)&Bs[wn + j * 16 + lm][k0 + quad * 8];
        #pragma unroll
        for (int i = 0; i < 4; i++)
            #pragma unroll
            for (int j = 0; j < 4; j++)
                acc[i][j] = __builtin_amdgcn_mfma_f32_16x16x32_bf16(af[i], bfr[j], acc[i][j], 0, 0, 0);
    }

    // epilogue: LDS transpose (reuse As), two 64-row halves, coalesced uint4.
    // C/D layout: col = lane&15, row = quad*4 + reg.
    u16* Cp = (bn < split) ? (Cb + bn) : (Cb2 + (bn - split));
    u16 (*St)[136] = (u16(*)[136])&As[0][0];  // 64 x 136 u16 = 17.4KB
    #pragma unroll
    for (int halfrow = 0; halfrow < 2; ++halfrow) {
        __syncthreads();
        if ((wv & 1) == halfrow) {
            #pragma unroll
            for (int i = 0; i < 4; i++) {
                int lr = i * 16 + quad * 4;
                #pragma unroll
                for (int j = 0; j < 4; j++) {
                    int lc = wn + j * 16 + lm;
                    #pragma unroll
                    for (int r = 0; r < 4; r++)
                        St[lr + r][lc] = f2b(acc[i][j][r]);
                }
            }
        }
        __syncthreads();
        #pragma unroll
        for (int it = 0; it < 4; ++it) {
            int idx = tid + it * 256;           // 0..1023
            int row = idx >> 4, seg = idx & 15; // 64 rows x 16 uint4
            int grow = bm + halfrow * 64 + row;
            if (grow < M)
                *(uint4*)(Cp + (size_t)grow * ldc + seg * 8) = *(const uint4*)&St[row][seg * 8];
        }
    }
}

// ---------------- skinny GEMM (layer 3): C[count,121] = A[count,1536] @ B[128,1536]^T ----
// register double-buffer on the 48-step K loop (R14).

__global__ __launch_bounds__(256) void gemm_skinny64(
    const u16* __restrict__ A, const u16* __restrict__ B,
    float* __restrict__ C, const float* __restrict__ bias, int count) {
    __shared__ __align__(16) u16 As[64][40];
    __shared__ __align__(16) u16 Bs[128][40];
    int tid = threadIdx.x, lane = tid & 63, wv = tid >> 6;
    int quad = lane >> 4, lm = lane & 15;
    int bm = blockIdx.x * 64;
    int mrow = (wv >> 1) * 32, ncol = (wv & 1) * 64;
    int ar = bm + (tid >> 2);
    if (ar >= count) ar = count - 1;
    const u16* Ap = A + (size_t)ar * 1536 + (tid & 3) * 8;
    int brow0 = tid >> 2, bseg0 = (tid & 3) * 8;
    int brow1 = (tid + 256) >> 2, bseg1 = ((tid + 256) & 3) * 8;
    const u16* Bp0 = B + (size_t)brow0 * 1536 + bseg0;
    const u16* Bp1 = B + (size_t)brow1 * 1536 + bseg1;

    f32x4 zero = {0.f, 0.f, 0.f, 0.f};
    f32x4 acc[2][4];
    #pragma unroll
    for (int i = 0; i < 2; i++)
        #pragma unroll
        for (int j = 0; j < 4; j++) acc[i][j] = zero;

    uint4 pa = *(const uint4*)(Ap);
    uint4 pb0 = *(const uint4*)(Bp0);
    uint4 pb1 = *(const uint4*)(Bp1);

    for (int k0 = 0; k0 < 1536; k0 += 32) {
        *(uint4*)&As[tid >> 2][(tid & 3) * 8] = pa;
        *(uint4*)&Bs[brow0][bseg0] = pb0;
        *(uint4*)&Bs[brow1][bseg1] = pb1;
        __syncthreads();
        bool more = (k0 + 32) < 1536;
        if (more) {
            pa  = *(const uint4*)(Ap + k0 + 32);
            pb0 = *(const uint4*)(Bp0 + k0 + 32);
            pb1 = *(const uint4*)(Bp1 + k0 + 32);
        }
        bf16x8 af[2], bfr[4];
        #pragma unroll
        for (int i = 0; i < 2; i++) af[i] = *(const bf16x8*)&As[mrow + i * 16 + lm][quad * 8];
        #pragma unroll
        for (int j = 0; j < 4; j++) bfr[j] = *(const bf16x8*)&Bs[ncol + j * 16 + lm][quad * 8];
        #pragma unroll
        for (int i = 0; i < 2; i++)
            #pragma unroll
            for (int j = 0; j < 4; j++)
                acc[i][j] = __builtin_amdgcn_mfma_f32_16x16x32_bf16(af[i], bfr[j], acc[i][j], 0, 0, 0);
        __syncthreads();
    }

    #pragma unroll
    for (int i = 0; i < 2; i++) {
        #pragma unroll
        for (int j = 0; j < 4; j++) {
            int col = ncol + j * 16 + lm;
            if (col >= 121) continue;
            int row_base = bm + mrow + i * 16 + quad * 4;
            #pragma unroll
            for (int r = 0; r < 4; r++) {
                int row = row_base + r;
                if (row >= count) continue;
                float v = acc[i][j][r] + bias[col];
                v = 1.f / (1.f + __expf(-v));
                C[(size_t)row * 121 + col] = v;
            }
        }
    }
}

// ---------------- fused softmax+agg + NEXT-LAYER LOGITS, layers 1&2 ----------------
// al8 layout: [i][0..3]=src logits, [i][4..7]=dst logits.
// 8-edge main tier (4 uint4 gathers in flight) + 4-edge mid tier + pair tail.
// NH>0 epilogue (split-half): after the xor(32) reduce both halves hold the
// full row; half 0 computes logit heads [0,NH/2), half 1 [NH/2,NH).
// Macro params wt/dv (NOT w/d): .w field access must not be captured.

#define ACC8(wt, dv) \
    acc[0] = fmaf(wt, blo(dv.x), acc[0]); acc[1] = fmaf(wt, bhi(dv.x), acc[1]); \
    acc[2] = fmaf(wt, blo(dv.y), acc[2]); acc[3] = fmaf(wt, bhi(dv.y), acc[3]); \
    acc[4] = fmaf(wt, blo(dv.z), acc[4]); acc[5] = fmaf(wt, bhi(dv.z), acc[5]); \
    acc[6] = fmaf(wt, blo(dv.w), acc[6]); acc[7] = fmaf(wt, bhi(dv.w), acc[7]);

template <int NH>
__global__ __launch_bounds__(256) void agg4_fused(
    const u16* __restrict__ f, const float* __restrict__ al8,
    const int* __restrict__ row_ptr, const int* __restrict__ csr_src,
    const float* __restrict__ bias, const u16* __restrict__ resb,
    u16* __restrict__ outb, const float* __restrict__ qpost,
    float* __restrict__ alout, int n) {
    constexpr int NH2 = NH / 2;
    int wid = threadIdx.x >> 6, lane = threadIdx.x & 63;
    int i = blockIdx.x * 4 + wid;
    if (i >= n) return;
    int beg = row_ptr[i], end = row_ptr[i + 1];
    int h_st = lane >> 4;        // staging head
    int el = lane & 15;          // staging edge slot
    int half = lane >> 5;        // edge parity
    int c8 = (lane & 31) * 8;    // this lane's 8 channels
    int wsel = (lane & 24) << 1; // weight-shuffle source-lane base
    float ald_st = al8[(size_t)i * 8 + 4 + h_st];
    float acc[8] = {};
    float S = 0.f;
    for (int base = beg; base < end; base += 16) {
        int cnt = min(16, end - base);
        int idxv = csr_src[base + min(el, cnt - 1)];
        float av = al8[(size_t)idxv * 8 + h_st] + ald_st;
        av = av > 0.f ? av : 0.2f * av;
        float ex = __expf(fminf(av, 60.f));
        int e = 0;
        // main tier: 8 edges (4 per half-wave), 4 uint4 gathers in flight
        for (; e + 8 <= cnt; e += 8) {
            int s0 = __shfl(idxv, e + half);
            int s1 = __shfl(idxv, e + 2 + half);
            int s2 = __shfl(idxv, e + 4 + half);
            int s3 = __shfl(idxv, e + 6 + half);
            uint4 d0 = *(const uint4*)(f + (size_t)s0 * 256 + c8);
            uint4 d1 = *(const uint4*)(f + (size_t)s1 * 256 + c8);
            uint4 d2 = *(const uint4*)(f + (size_t)s2 * 256 + c8);
            uint4 d3 = *(const uint4*)(f + (size_t)s3 * 256 + c8);
            float w0 = __shfl(ex, wsel | (e + half));
            float w1 = __shfl(ex, wsel | (e + 2 + half));
            float w2 = __shfl(ex, wsel | (e + 4 + half));
            float w3 = __shfl(ex, wsel | (e + 6 + half));
            S += (w0 + w1) + (w2 + w3);
            ACC8(w0, d0);
            ACC8(w1, d1);
            ACC8(w2, d2);
            ACC8(w3, d3);
        }
        // mid tier: 4 edges, 2 gathers in flight
        for (; e + 4 <= cnt; e += 4) {
            int s0 = __shfl(idxv, e + half);
            int s1 = __shfl(idxv, e + 2 + half);
            uint4 d0 = *(const uint4*)(f + (size_t)s0 * 256 + c8);
            uint4 d1 = *(const uint4*)(f + (size_t)s1 * 256 + c8);
            float w0 = __shfl(ex, wsel | (e + half));
            float w1 = __shfl(ex, wsel | (e + 2 + half));
            S += w0 + w1;
            ACC8(w0, d0);
            ACC8(w1, d1);
        }
        // tail: pairs with clamp (<=3 edges left)
        for (; e < cnt; e += 2) {
            int ei = e + half;
            int eu = ei < cnt ? ei : e;
            int s = __shfl(idxv, eu);
            float w = __shfl(ex, wsel | eu);
            if (ei >= cnt) w = 0.f;
            S += w;
            uint4 d = *(const uint4*)(f + (size_t)s * 256 + c8);
            ACC8(w, d);
        }
    }
    #pragma unroll
    for (int k = 0; k < 8; k++) acc[k] += __shfl_xor(acc[k], 32);
    S += __shfl_xor(S, 32);
    // epilogue: BOTH halves now hold the full reduced row for their c8
    float inv = 1.f / (S + 1e-16f);
    float4 b0 = *(const float4*)(bias + c8);
    float4 b1 = *(const float4*)(bias + c8 + 4);
    float v[8];
    v[0] = acc[0] * inv + b0.x; v[1] = acc[1] * inv + b0.y;
    v[2] = acc[2] * inv + b0.z; v[3] = acc[3] * inv + b0.w;
    v[4] = acc[4] * inv + b1.x; v[5] = acc[5] * inv + b1.y;
    v[6] = acc[6] * inv + b1.z; v[7] = acc[7] * inv + b1.w;
    if (resb) {
        uint4 r = *(const uint4*)(resb + (size_t)i * 256 + c8);
        v[0] += blo(r.x); v[1] += bhi(r.x); v[2] += blo(r.y); v[3] += bhi(r.y);
        v[4] += blo(r.z); v[5] += bhi(r.z); v[6] += blo(r.w); v[7] += bhi(r.w);
    }
    #pragma unroll
    for (int k = 0; k < 8; k++) v[k] = v[k] > 0.f ? v[k] : (__expf(v[k]) - 1.f);  // ELU
    uint4 o;
    o.x = (unsigned)f2b(v[0]) | ((unsigned)f2b(v[1]) << 16);
    o.y = (unsigned)f2b(v[2]) | ((unsigned)f2b(v[3]) << 16);
    o.z = (unsigned)f2b(v[4]) | ((unsigned)f2b(v[5]) << 16);
    o.w = (unsigned)f2b(v[6]) | ((unsigned)f2b(v[7]) << 16);
    if (half == 0)
        *(uint4*)(outb + (size_t)i * 256 + c8) = o;
    if (NH > 0) {
        // next-layer logits from the bf16-ROUNDED row. Half 0 computes heads
        // [0,NH2), half 1 heads [NH2,NH); xor<32 reduce stays within a half.
        float rv[8];
        rv[0] = blo(o.x); rv[1] = bhi(o.x); rv[2] = blo(o.y); rv[3] = bhi(o.y);
        rv[4] = blo(o.z); rv[5] = bhi(o.z); rv[6] = blo(o.w); rv[7] = bhi(o.w);
        int hbase = half * NH2;
        float p[NH2 > 0 ? NH2 : 1];
        #pragma unroll
        for (int h = 0; h < NH2; h++) {
            const float* qp = qpost + (size_t)(hbase + h) * 256 + c8;
            float4 qa = *(const float4*)(qp);
            float4 qb = *(const float4*)(qp + 4);
            p[h] = rv[0] * qa.x + rv[1] * qa.y + rv[2] * qa.z + rv[3] * qa.w
                 + rv[4] * qb.x + rv[5] * qb.y + rv[6] * qb.z + rv[7] * qb.w;
        }
        #pragma unroll
        for (int ofs = 1; ofs <= 16; ofs <<= 1) {
            #pragma unroll
            for (int h = 0; h < NH2; h++) p[h] += __shfl_xor(p[h], ofs);
        }
        if ((lane & 31) == 0) {
            float* ap = alout + (size_t)i * NH + hbase;
            if (NH2 == 4) {
                *(float4*)ap = make_float4(p[0], p[1], p[2], p[3]);
            } else if (NH2 == 6) {
                if (half == 0) {
                    *(float4*)ap = make_float4(p[0], p[1], p[2], p[3]);
                    *(float2*)(ap + 4) = make_float2(p[4], p[5]);
                } else {
                    *(float2*)ap = make_float2(p[0], p[1]);
                    *(float4*)(ap + 2) = make_float4(p[2], p[3], p[4], p[5]);
                }
            } else {
                #pragma unroll
                for (int h = 0; h < NH2; h++) ap[h] = p[h];
            }
        }
    }
}

// ---------------- fused softmax+agg, layer 3 (6 heads): WAVE per node ----------------
// Ssum hoisted to a per-batch 16-lane shuffle reduction at staging.

__global__ __launch_bounds__(256) void aggS_fused(
    const u16* __restrict__ x, const float* __restrict__ al3,
    const int* __restrict__ row_ptr, const int* __restrict__ csr_src,
    u16* __restrict__ S, int node0, int count) {
    __shared__ int s_i[4][16];
    __shared__ float s_w[4][96];
    __shared__ float s_sum[4][6];
    int wid = threadIdx.x >> 6, lane = threadIdx.x & 63;
    int li = blockIdx.x * 4 + wid;
    if (li >= count) return;
    int i = node0 + li;
    int beg = row_ptr[i], end = row_ptr[i + 1];
    int c4 = lane * 4;
    int e16 = lane & 15;
    int hA = lane >> 4;            // heads 0-3 staging
    int hB = 4 + (lane >> 4);      // heads 4-5 staging (lanes 0-31)
    float aldA = al3[(size_t)i * 12 + 6 + hA];
    float aldB = (lane < 32) ? al3[(size_t)i * 12 + 6 + hB] : 0.f;
    float acc[6][4] = {};
    if (lane < 6) s_sum[wid][lane] = 0.f;
    for (int base = beg; base < end; base += 16) {
        int cnt = min(16, end - base);
        int idxe = csr_src[base + min(e16, cnt - 1)];
        if (lane < 16) s_i[wid][lane] = idxe;
        float vA = al3[(size_t)idxe * 12 + hA] + aldA;
        vA = vA > 0.f ? vA : 0.2f * vA;
        float exA = __expf(fminf(vA, 60.f));
        if (e16 < cnt) s_w[wid][e16 * 6 + hA] = exA;
        float exB = 0.f;
        if (lane < 32) {
            float vB = al3[(size_t)idxe * 12 + hB] + aldB;
            vB = vB > 0.f ? vB : 0.2f * vB;
            exB = __expf(fminf(vB, 60.f));
            if (e16 < cnt) s_w[wid][e16 * 6 + hB] = exB;
        }
        // per-batch head sums via 16-lane group reduction
        float sA = (e16 < cnt) ? exA : 0.f;
        sA += __shfl_xor(sA, 1); sA += __shfl_xor(sA, 2);
        sA += __shfl_xor(sA, 4); sA += __shfl_xor(sA, 8);
        float sB = (lane < 32 && e16 < cnt) ? exB : 0.f;
        sB += __shfl_xor(sB, 1); sB += __shfl_xor(sB, 2);
        sB += __shfl_xor(sB, 4); sB += __shfl_xor(sB, 8);
        if (e16 == 0) {
            s_sum[wid][hA] += sA;                    // lanes 0,16,32,48 -> heads 0-3
            if (lane < 32) s_sum[wid][hB] += sB;     // lanes 0,16     -> heads 4-5
        }
        // wave-coherent LDS (lockstep), no barrier
        int e = 0;
        for (; e + 4 <= cnt; e += 4) {
            int s0 = s_i[wid][e],     s1 = s_i[wid][e + 1];
            int s2 = s_i[wid][e + 2], s3 = s_i[wid][e + 3];
            uint2 d0 = *(const uint2*)(x + (size_t)s0 * 256 + c4);
            uint2 d1 = *(const uint2*)(x + (size_t)s1 * 256 + c4);
            uint2 d2 = *(const uint2*)(x + (size_t)s2 * 256 + c4);
            uint2 d3 = *(const uint2*)(x + (size_t)s3 * 256 + c4);
            float f00 = blo(d0.x), f01 = bhi(d0.x), f02 = blo(d0.y), f03 = bhi(d0.y);
            float f10 = blo(d1.x), f11 = bhi(d1.x), f12 = blo(d1.y), f13 = bhi(d1.y);
            float f20 = blo(d2.x), f21 = bhi(d2.x), f22 = blo(d2.y), f23 = bhi(d2.y);
            float f30 = blo(d3.x), f31 = bhi(d3.x), f32 = blo(d3.y), f33 = bhi(d3.y);
            #pragma unroll
            for (int hh = 0; hh < 6; hh++) {
                float w0 = s_w[wid][e * 6 + hh];
                float w1 = s_w[wid][(e + 1) * 6 + hh];
                float w2 = s_w[wid][(e + 2) * 6 + hh];
                float w3 = s_w[wid][(e + 3) * 6 + hh];
                acc[hh][0] = fmaf(w0, f00, acc[hh][0]);
                acc[hh][1] = fmaf(w0, f01, acc[hh][1]);
                acc[hh][2] = fmaf(w0, f02, acc[hh][2]);
                acc[hh][3] = fmaf(w0, f03, acc[hh][3]);
                acc[hh][0] = fmaf(w1, f10, acc[hh][0]);
                acc[hh][1] = fmaf(w1, f11, acc[hh][1]);
                acc[hh][2] = fmaf(w1, f12, acc[hh][2]);
                acc[hh][3] = fmaf(w1, f13, acc[hh][3]);
                acc[hh][0] = fmaf(w2, f20, acc[hh][0]);
                acc[hh][1] = fmaf(w2, f21, acc[hh][1]);
                acc[hh][2] = fmaf(w2, f22, acc[hh][2]);
                acc[hh][3] = fmaf(w2, f23, acc[hh][3]);
                acc[hh][0] = fmaf(w3, f30, acc[hh][0]);
                acc[hh][1] = fmaf(w3, f31, acc[hh][1]);
                acc[hh][2] = fmaf(w3, f32, acc[hh][2]);
                acc[hh][3] = fmaf(w3, f33, acc[hh][3]);
            }
        }
        for (; e < cnt; e++) {
            int s = s_i[wid][e];
            uint2 d = *(const uint2*)(x + (size_t)s * 256 + c4);
            float v0 = blo(d.x), v1 = bhi(d.x), v2 = blo(d.y), v3 = bhi(d.y);
            #pragma unroll
            for (int hh = 0; hh < 6; hh++) {
                float w = s_w[wid][e * 6 + hh];
                acc[hh][0] = fmaf(w, v0, acc[hh][0]);
                acc[hh][1] = fmaf(w, v1, acc[hh][1]);
                acc[hh][2] = fmaf(w, v2, acc[hh][2]);
                acc[hh][3] = fmaf(w, v3, acc[hh][3]);
            }
        }
    }
    #pragma unroll
    for (int hh = 0; hh < 6; hh++) {
        float inv = 1.f / (6.f * (s_sum[wid][hh] + 1e-16f));
        ushort4 o;
        o.x = f2b(acc[hh][0] * inv);
        o.y = f2b(acc[hh][1] * inv);
        o.z = f2b(acc[hh][2] * inv);
        o.w = f2b(acc[hh][3] * inv);
        *(ushort4*)(S + (size_t)li * 1536 + hh * 256 + c4) = o;
    }
}

// ---------------- host ----------------

extern "C" void kernel_launch(void* const* d_in, const int* in_sizes, int n_in,
                              void* d_out, int out_size, void* d_ws, size_t ws_size,
                              hipStream_t stream) {
    const float* x      = (const float*)d_in[0];
    const int*   src    = (const int*)d_in[1];
    const int*   dst    = (const int*)d_in[2];
    const float* W1     = (const float*)d_in[3];
    const float* a1_src = (const float*)d_in[4];
    const float* a1_dst = (const float*)d_in[5];
    const float* b1     = (const float*)d_in[6];
    const float* W2     = (const float*)d_in[7];
    const float* a2_src = (const float*)d_in[8];
    const float* a2_dst = (const float*)d_in[9];
    const float* b2     = (const float*)d_in[10];
    const float* Wres2  = (const float*)d_in[11];
    const float* W3     = (const float*)d_in[12];
    const float* a3_src = (const float*)d_in[13];
    const float* a3_dst = (const float*)d_in[14];
    const float* b3     = (const float*)d_in[15];
    float* out = (float*)d_out;

    const int N = NODES, E = EDGES;
    const int EN = E + N;
    const int NB = (N + 255) / 256;  // 196
    const int NRT = MPAD / 128;      // 391 row tiles

    char* p = (char*)d_ws;
    auto alloc = [&](size_t bytes) -> char* {
        char* r = p;
        p += (bytes + 511) & ~(size_t)511;
        return r;
    };
    // persistent
    int*   row_ptr = (int*)alloc((size_t)(N + 1) * sizeof(int));
    int*   cursor  = (int*)alloc((size_t)N * sizeof(int));
    int*   deg     = (int*)alloc((size_t)N * sizeof(int));
    int*   bsum    = (int*)alloc(256 * sizeof(int));
    int*   csr_src = (int*)alloc((size_t)EN * sizeof(int));
    float* alA     = (float*)alloc((size_t)N * 8 * sizeof(float));
    float* alB     = (float*)alloc((size_t)N * 8 * sizeof(float));
    float* al3     = (float*)alloc((size_t)N * 12 * sizeof(float));
    float* q1t     = (float*)alloc((size_t)8 * 128 * sizeof(float));
    float* q2t     = (float*)alloc((size_t)8 * 256 * sizeof(float));
    float* cm      = (float*)alloc((size_t)12 * 256 * sizeof(float));
    u16*   WT1     = (u16*)alloc((size_t)256 * 128 * sizeof(u16));
    u16*   WT2     = (u16*)alloc((size_t)512 * 256 * sizeof(u16));
    u16*   W3sT    = (u16*)alloc((size_t)128 * 1536 * sizeof(u16));
    u16*   o2b     = (u16*)alloc((size_t)MPAD * 256 * sizeof(u16));
    // region2 (phase-overlaid)
    const size_t A2B_B  = (size_t)MPAD * 256 * sizeof(u16);
    const size_t F1B_B  = (size_t)N * 256 * sizeof(u16);
    const size_t RESB_B = (size_t)N * 256 * sizeof(u16);
    const size_t S_B    = (size_t)C0 * 1536 * sizeof(u16);
    size_t r2_bytes = A2B_B + F1B_B + RESB_B;
    if (S_B > r2_bytes) r2_bytes = S_B;
    char* r2 = alloc(r2_bytes + 1024);
    u16* A2b  = (u16*)r2;                        // layer-1 out bf16 [MPAD,256]
    u16* f1b  = (u16*)(r2 + A2B_B);              // layer feat bf16 [N,256]
    u16* resb = (u16*)(r2 + A2B_B + F1B_B);      // layer-2 residual bf16 [N,256]
    u16* A2a  = (u16*)(r2 + A2B_B + F1B_B);      // x bf16 [MPAD,128] (dead before resb)
    u16* Sb   = (u16*)r2;                        // S chunk bf16 [C0,1536] (layer 3)
    (void)ws_size; (void)n_in; (void)in_sizes; (void)out_size;

    // --- CSR build ---
    fill_ones_kernel<<<NB, 256, 0, stream>>>(deg, N);
    hist_kernel<<<(E + 255) / 256, 256, 0, stream>>>(dst, deg, E);
    deg_bsum_kernel<<<NB, 256, 0, stream>>>(deg, bsum, N);
    bsum_scan_kernel<<<1, 256, 0, stream>>>(bsum, row_ptr, NB, N);
    deg_scan_kernel<<<NB, 256, 0, stream>>>(deg, bsum, row_ptr, cursor, N);
    scatter_kernel<<<(E + N + 255) / 256, 256, 0, stream>>>(src, dst, E, N, cursor, csr_src);

    int nwb = (N + 3) / 4;

    // --- all weight prep in one launch ---
    prep_weights<<<(PREP_TOTAL + 255) / 256, 256, 0, stream>>>(
        W1, W2, Wres2, W3, a1_src, a1_dst, a2_src, a2_dst, a3_src, a3_dst,
        WT1, WT2, W3sT, q1t, q2t, cm);

    // --- layer 1: 128 -> 4x64 concat, ELU ---
    convx_al1<<<nwb, 256, 0, stream>>>(x, q1t, A2a, alA, N);
    {
        int nblk = 8 * ((NRT + 7) / 8) * 2;   // XCD-swizzled 1D grid, NT=2
        gemm_fullk<128, 2><<<nblk, 256, 0, stream>>>(A2a, WT1, f1b, nullptr,
                                                     N, 256, 9999, NRT);
    }
    // agg + fused layer-2 logits (alB = rounded_out . q2t)
    agg4_fused<8><<<nwb, 256, 0, stream>>>(f1b, alA, row_ptr, csr_src, b1, nullptr,
                                           A2b, q2t, alB, N);

    // --- layer 2: 256 -> 4x64 concat + residual (one 512-wide GEMM), ELU ---
    {
        int nblk = 8 * ((NRT + 7) / 8) * 4;   // NT=4
        gemm_fullk<256, 4><<<nblk, 256, 0, stream>>>(A2b, WT2, f1b, resb,
                                                     N, 256, 256, NRT);
    }
    // agg + fused layer-3 logits (al3 = rounded_out . cm)
    agg4_fused<12><<<nwb, 256, 0, stream>>>(f1b, alB, row_ptr, csr_src, b2, resb,
                                            o2b, cm, al3, N);

    // --- layer 3: fused softmax+input-space agg -> skinny GEMM ---
    {
        aggS_fused<<<(C0 + 3) / 4, 256, 0, stream>>>(o2b, al3, row_ptr, csr_src, Sb, 0, C0);
        gemm_skinny64<<<(C0 + 63) / 64, 256, 0, stream>>>(Sb, W3sT, out, b3, C0);
        aggS_fused<<<(C1 + 3) / 4, 256, 0, stream>>>(o2b, al3, row_ptr, csr_src, Sb, C0, C1);
        gemm_skinny64<<<(C1 + 63) / 64, 256, 0, stream>>>(Sb, W3sT, out + (size_t)C0 * 121, b3, C1);
    }
}

// Round 11
// 599.531 us; speedup vs baseline: 1.0161x; 1.0161x over previous
//
#include <hip/hip_runtime.h>
#include <hip/hip_bf16.h>

// PPI GAT, 3 layers. N=50000, E=800000 (+N self loops), avg degree ~17.
// R16: R15 (full-K LDS gemm, 1 block/CU) REGRESSED 598->609 — occupancy
// bought with LDS is a bad trade (matches m132). Reverted to R14's proven
// gemm (reg double-buffer + XCD-swizzled 1D grid, 20KB LDS). Kept: all of
// R12/R14 (split-half logit epilogue, aggS Ssum hoist, reg-dbuf skinny).
// New (low-risk): CSR chain shortened — deg zeroed via hipMemsetAsync and
// the self-loop count folded into hist_kernel (E+N threads); one fewer
// dispatch + one fewer full-N write pass.

#define NODES 50000
#define EDGES 800000
#define MPAD  50048            // ceil(N/128)*128
#define C0    25088            // layer-3 chunk-0 rows
#define C1    24912            // layer-3 chunk-1 rows

typedef unsigned short u16;
typedef __attribute__((ext_vector_type(8))) short bf16x8;
typedef __attribute__((ext_vector_type(4))) float f32x4;

__device__ __forceinline__ float bf16f(u16 r) {
    return __uint_as_float(((unsigned)r) << 16);
}
__device__ __forceinline__ u16 f2b(float v) {
    __hip_bfloat16 b = __float2bfloat16(v);
    return *(u16*)&b;
}
__device__ __forceinline__ float blo(unsigned d) { return __uint_as_float(d << 16); }
__device__ __forceinline__ float bhi(unsigned d) { return __uint_as_float(d & 0xffff0000u); }

// ---------------- CSR build ----------------

// deg pre-zeroed by hipMemsetAsync; counts edges AND self-loops in one pass.
__global__ void hist_kernel(const int* __restrict__ dst, int* __restrict__ deg,
                            int E, int n) {
    int e = blockIdx.x * blockDim.x + threadIdx.x;
    if (e < E) atomicAdd(&deg[dst[e]], 1);
    else if (e < E + n) atomicAdd(&deg[e - E], 1);  // self-loop
}

__global__ void deg_bsum_kernel(const int* __restrict__ deg, int* __restrict__ bsum, int n) {
    int tid = threadIdx.x, lane = tid & 63, wid = tid >> 6;
    int i = blockIdx.x * 256 + tid;
    int v = (i < n) ? deg[i] : 0;
    #pragma unroll
    for (int ofs = 32; ofs > 0; ofs >>= 1) v += __shfl_down(v, ofs);
    __shared__ int sp[4];
    if (lane == 0) sp[wid] = v;
    __syncthreads();
    if (tid == 0) bsum[blockIdx.x] = sp[0] + sp[1] + sp[2] + sp[3];
}

__global__ void bsum_scan_kernel(int* __restrict__ bsum, int* __restrict__ row_ptr,
                                 int nb, int n) {
    int tid = threadIdx.x, lane = tid & 63, wid = tid >> 6;
    int v = (tid < nb) ? bsum[tid] : 0;
    int incl = v;
    #pragma unroll
    for (int ofs = 1; ofs < 64; ofs <<= 1) {
        int t = __shfl_up(incl, ofs);
        if (lane >= ofs) incl += t;
    }
    __shared__ int sp[4];
    if (lane == 63) sp[wid] = incl;
    __syncthreads();
    int add = 0;
    for (int k = 0; k < wid; k++) add += sp[k];
    int excl = incl - v + add;
    if (tid < nb) bsum[tid] = excl;
    if (tid == nb - 1) row_ptr[n] = excl + v;
}

__global__ void deg_scan_kernel(const int* __restrict__ deg, const int* __restrict__ bofs,
                                int* __restrict__ row_ptr, int* __restrict__ cursor, int n) {
    int tid = threadIdx.x, lane = tid & 63, wid = tid >> 6;
    int i = blockIdx.x * 256 + tid;
    int v = (i < n) ? deg[i] : 0;
    int incl = v;
    #pragma unroll
    for (int ofs = 1; ofs < 64; ofs <<= 1) {
        int t = __shfl_up(incl, ofs);
        if (lane >= ofs) incl += t;
    }
    __shared__ int sp[4];
    if (lane == 63) sp[wid] = incl;
    __syncthreads();
    int add = bofs[blockIdx.x];
    for (int k = 0; k < wid; k++) add += sp[k];
    int excl = incl - v + add;
    if (i < n) { row_ptr[i] = excl; cursor[i] = excl; }
}

__global__ void scatter_kernel(const int* __restrict__ src, const int* __restrict__ dst,
                               int E, int n, int* __restrict__ cursor, int* __restrict__ csr_src) {
    int e = blockIdx.x * blockDim.x + threadIdx.x;
    if (e < E) {
        int d = dst[e];
        int p = atomicAdd(&cursor[d], 1);
        csr_src[p] = src[e];
    } else if (e < E + n) {
        int i = e - E;
        int p = atomicAdd(&cursor[i], 1);
        csr_src[p] = i;  // self-loop
    }
}

// ---------------- prep: all weight converts + q-vectors, one launch ----------------

__global__ void prep_weights(
    const float* __restrict__ W1, const float* __restrict__ W2,
    const float* __restrict__ Wres2, const float* __restrict__ W3,
    const float* __restrict__ a1s, const float* __restrict__ a1d,
    const float* __restrict__ a2s, const float* __restrict__ a2d,
    const float* __restrict__ a3s, const float* __restrict__ a3d,
    u16* __restrict__ WT1, u16* __restrict__ WT2, u16* __restrict__ W3sT,
    float* __restrict__ q1t, float* __restrict__ q2t, float* __restrict__ cm) {
    int idx = blockIdx.x * 256 + threadIdx.x;
    if (idx < 32768) {                        // WT1
        int n = idx >> 7, k = idx & 127;
        WT1[idx] = f2b(W1[(size_t)k * 256 + n]);
    } else if ((idx -= 32768) < 131072) {     // WT2 = [W2 | Wres2]
        int n = idx >> 8, k = idx & 255;
        float v = (n < 256) ? W2[(size_t)k * 256 + n] : Wres2[(size_t)k * 256 + (n - 256)];
        WT2[idx] = f2b(v);
    } else if ((idx -= 131072) < 196608) {    // W3sT
        int n = idx / 1536, q = idx % 1536;
        int h = q >> 8, k = q & 255;
        W3sT[idx] = f2b((n < 121) ? W3[(size_t)k * 726 + h * 121 + n] : 0.f);
    } else if ((idx -= 196608) < 1024) {      // q1t
        int h = idx >> 7, k = idx & 127;
        int hh = h & 3;
        const float* a = (h < 4) ? a1s : a1d;
        float v = 0.f;
        for (int c = 0; c < 64; c++) v += W1[(size_t)k * 256 + hh * 64 + c] * a[hh * 64 + c];
        q1t[idx] = v;
    } else if ((idx -= 1024) < 2048) {        // q2t [8][256]
        int h = idx >> 8, k = idx & 255;
        int hh = h & 3;
        const float* a = (h < 4) ? a2s : a2d;
        float v = 0.f;
        for (int c = 0; c < 64; c++) v += W2[(size_t)k * 256 + hh * 64 + c] * a[hh * 64 + c];
        q2t[idx] = v;
    } else if ((idx -= 2048) < 3072) {        // cm [12][256]
        int o = idx >> 8, k = idx & 255;
        int h = (o < 6) ? o : o - 6;
        const float* a = (o < 6) ? a3s : a3d;
        float v = 0.f;
        for (int c = 0; c < 121; c++) v += W3[(size_t)k * 726 + h * 121 + c] * a[h * 121 + c];
        cm[idx] = v;
    }
}
#define PREP_TOTAL (32768 + 131072 + 196608 + 1024 + 2048 + 3072)

// ---------------- convx + layer-1 logits: wave per node ----------------

__global__ __launch_bounds__(256) void convx_al1(
    const float* __restrict__ x, const float* __restrict__ q1t,
    u16* __restrict__ A2a, float* __restrict__ alA, int n) {
    int wid = threadIdx.x >> 6, lane = threadIdx.x & 63;
    int i = blockIdx.x * 4 + wid;
    if (i >= n) return;
    float2 xv = *(const float2*)(x + (size_t)i * 128 + lane * 2);
    ushort2 o;
    o.x = f2b(xv.x); o.y = f2b(xv.y);
    *(ushort2*)(A2a + (size_t)i * 128 + lane * 2) = o;
    float p[8];
    #pragma unroll
    for (int h = 0; h < 8; h++) {
        float2 q = *(const float2*)(q1t + h * 128 + lane * 2);
        p[h] = xv.x * q.x + xv.y * q.y;
    }
    #pragma unroll
    for (int ofs = 1; ofs <= 32; ofs <<= 1) {
        #pragma unroll
        for (int h = 0; h < 8; h++) p[h] += __shfl_xor(p[h], ofs);
    }
    if (lane == 0) {
        *(float4*)(alA + (size_t)i * 8)     = make_float4(p[0], p[1], p[2], p[3]);
        *(float4*)(alA + (size_t)i * 8 + 4) = make_float4(p[4], p[5], p[6], p[7]);
    }
}

// ---------------- bf16 MFMA GEMM: C = A @ B^T, bf16 out, col split ----------------
// R14 form: 1D grid, XCD swizzle (x=b&7): per-XCD consecutive blocks cover
// all NT col-tiles of one A row-panel -> panel lives in exactly one L2.
// Register double-buffer: K-tile t+1 prefetched into regs during tile t's
// MFMAs. LDS-transpose epilogue with coalesced uint4 stores.

__global__ __launch_bounds__(256) void gemm_mfma_kernel(
    const u16* __restrict__ A, const u16* __restrict__ B,
    u16* __restrict__ Cb, u16* __restrict__ Cb2,
    int M, int K2, int ldc, int split, int NT, int nrt) {
    __shared__ __align__(16) u16 smem[2][128][40];
    #define As smem[0]
    #define Bs smem[1]
    int b = blockIdx.x;
    int xcd = b & 7, q = b >> 3;
    int ct = q % NT, rb = q / NT;
    int rt = rb * 8 + xcd;
    if (rt >= nrt) return;
    int bm = rt * 128, bn = ct * 128;

    int tid = threadIdx.x;
    int lane = tid & 63;
    int wv = tid >> 6;
    int quad = lane >> 4, lm = lane & 15;
    int wm = (wv & 1) * 64, wn = (wv >> 1) * 64;

    int lrow0 = tid >> 2, lseg0 = (tid & 3) * 8;
    int lrow1 = (tid + 256) >> 2, lseg1 = ((tid + 256) & 3) * 8;
    const u16* Ap0 = A + (size_t)(bm + lrow0) * K2 + lseg0;
    const u16* Ap1 = A + (size_t)(bm + lrow1) * K2 + lseg1;
    const u16* Bp0 = B + (size_t)(bn + lrow0) * K2 + lseg0;
    const u16* Bp1 = B + (size_t)(bn + lrow1) * K2 + lseg1;

    f32x4 zero = {0.f, 0.f, 0.f, 0.f};
    f32x4 acc[4][4];
    #pragma unroll
    for (int i = 0; i < 4; i++)
        #pragma unroll
        for (int j = 0; j < 4; j++) acc[i][j] = zero;

    // prologue: prefetch tile 0
    uint4 pa0 = *(const uint4*)(Ap0), pa1 = *(const uint4*)(Ap1);
    uint4 pb0 = *(const uint4*)(Bp0), pb1 = *(const uint4*)(Bp1);

    for (int k0 = 0; k0 < K2; k0 += 32) {
        *(uint4*)&As[lrow0][lseg0] = pa0;
        *(uint4*)&As[lrow1][lseg1] = pa1;
        *(uint4*)&Bs[lrow0][lseg0] = pb0;
        *(uint4*)&Bs[lrow1][lseg1] = pb1;
        __syncthreads();
        bool more = (k0 + 32) < K2;
        if (more) {
            pa0 = *(const uint4*)(Ap0 + k0 + 32);
            pa1 = *(const uint4*)(Ap1 + k0 + 32);
            pb0 = *(const uint4*)(Bp0 + k0 + 32);
            pb1 = *(const uint4*)(Bp1 + k0 + 32);
        }
        bf16x8 af[4], bfr[4];
        #pragma unroll
        for (int i = 0; i < 4; i++) af[i] = *(const bf16x8*)&As[wm + i * 16 + lm][quad * 8];
        #pragma unroll
        for (int j = 0; j < 4; j++) bfr[j] = *(const bf16x8*)&Bs[wn + j * 16 + lm][quad * 8];
        #pragma unroll
        for (int i = 0; i < 4; i++)
            #pragma unroll
            for (int j = 0; j < 4; j++)
                acc[i][j] = __builtin_amdgcn_mfma_f32_16x16x32_bf16(af[i], bfr[j], acc[i][j], 0, 0, 0);
        __syncthreads();
    }

    // epilogue: LDS transpose, two 64-row halves, coalesced uint4 stores.
    // C/D layout: col = lane&15, row = quad*4 + reg.
    u16* Cp = (bn < split) ? (Cb + bn) : (Cb2 + (bn - split));
    u16 (*St)[136] = (u16(*)[136])&smem[0][0][0];  // 64 x 136 u16 = 17408B
    #pragma unroll
    for (int halfrow = 0; halfrow < 2; ++halfrow) {
        __syncthreads();
        if ((wv & 1) == halfrow) {
            #pragma unroll
            for (int i = 0; i < 4; i++) {
                int lr = i * 16 + quad * 4;
                #pragma unroll
                for (int j = 0; j < 4; j++) {
                    int lc = wn + j * 16 + lm;
                    #pragma unroll
                    for (int r = 0; r < 4; r++)
                        St[lr + r][lc] = f2b(acc[i][j][r]);
                }
            }
        }
        __syncthreads();
        #pragma unroll
        for (int it = 0; it < 4; ++it) {
            int idx = tid + it * 256;           // 0..1023
            int row = idx >> 4, seg = idx & 15; // 64 rows x 16 uint4
            int grow = bm + halfrow * 64 + row;
            if (grow < M)
                *(uint4*)(Cp + (size_t)grow * ldc + seg * 8) = *(const uint4*)&St[row][seg * 8];
        }
    }
    #undef As
    #undef Bs
}

// ---------------- skinny GEMM (layer 3): C[count,121] = A[count,1536] @ B[128,1536]^T ----
// register double-buffer on the 48-step K loop (R14).

__global__ __launch_bounds__(256) void gemm_skinny64(
    const u16* __restrict__ A, const u16* __restrict__ B,
    float* __restrict__ C, const float* __restrict__ bias, int count) {
    __shared__ __align__(16) u16 As[64][40];
    __shared__ __align__(16) u16 Bs[128][40];
    int tid = threadIdx.x, lane = tid & 63, wv = tid >> 6;
    int quad = lane >> 4, lm = lane & 15;
    int bm = blockIdx.x * 64;
    int mrow = (wv >> 1) * 32, ncol = (wv & 1) * 64;
    int ar = bm + (tid >> 2);
    if (ar >= count) ar = count - 1;
    const u16* Ap = A + (size_t)ar * 1536 + (tid & 3) * 8;
    int brow0 = tid >> 2, bseg0 = (tid & 3) * 8;
    int brow1 = (tid + 256) >> 2, bseg1 = ((tid + 256) & 3) * 8;
    const u16* Bp0 = B + (size_t)brow0 * 1536 + bseg0;
    const u16* Bp1 = B + (size_t)brow1 * 1536 + bseg1;

    f32x4 zero = {0.f, 0.f, 0.f, 0.f};
    f32x4 acc[2][4];
    #pragma unroll
    for (int i = 0; i < 2; i++)
        #pragma unroll
        for (int j = 0; j < 4; j++) acc[i][j] = zero;

    uint4 pa = *(const uint4*)(Ap);
    uint4 pb0 = *(const uint4*)(Bp0);
    uint4 pb1 = *(const uint4*)(Bp1);

    for (int k0 = 0; k0 < 1536; k0 += 32) {
        *(uint4*)&As[tid >> 2][(tid & 3) * 8] = pa;
        *(uint4*)&Bs[brow0][bseg0] = pb0;
        *(uint4*)&Bs[brow1][bseg1] = pb1;
        __syncthreads();
        bool more = (k0 + 32) < 1536;
        if (more) {
            pa  = *(const uint4*)(Ap + k0 + 32);
            pb0 = *(const uint4*)(Bp0 + k0 + 32);
            pb1 = *(const uint4*)(Bp1 + k0 + 32);
        }
        bf16x8 af[2], bfr[4];
        #pragma unroll
        for (int i = 0; i < 2; i++) af[i] = *(const bf16x8*)&As[mrow + i * 16 + lm][quad * 8];
        #pragma unroll
        for (int j = 0; j < 4; j++) bfr[j] = *(const bf16x8*)&Bs[ncol + j * 16 + lm][quad * 8];
        #pragma unroll
        for (int i = 0; i < 2; i++)
            #pragma unroll
            for (int j = 0; j < 4; j++)
                acc[i][j] = __builtin_amdgcn_mfma_f32_16x16x32_bf16(af[i], bfr[j], acc[i][j], 0, 0, 0);
        __syncthreads();
    }

    #pragma unroll
    for (int i = 0; i < 2; i++) {
        #pragma unroll
        for (int j = 0; j < 4; j++) {
            int col = ncol + j * 16 + lm;
            if (col >= 121) continue;
            int row_base = bm + mrow + i * 16 + quad * 4;
            #pragma unroll
            for (int r = 0; r < 4; r++) {
                int row = row_base + r;
                if (row >= count) continue;
                float v = acc[i][j][r] + bias[col];
                v = 1.f / (1.f + __expf(-v));
                C[(size_t)row * 121 + col] = v;
            }
        }
    }
}

// ---------------- fused softmax+agg + NEXT-LAYER LOGITS, layers 1&2 ----------------
// al8 layout: [i][0..3]=src logits, [i][4..7]=dst logits.
// 8-edge main tier (4 uint4 gathers in flight) + 4-edge mid tier + pair tail.
// NH>0 epilogue (split-half): after the xor(32) reduce both halves hold the
// full row; half 0 computes logit heads [0,NH/2), half 1 [NH/2,NH).
// Macro params wt/dv (NOT w/d): .w field access must not be captured.

#define ACC8(wt, dv) \
    acc[0] = fmaf(wt, blo(dv.x), acc[0]); acc[1] = fmaf(wt, bhi(dv.x), acc[1]); \
    acc[2] = fmaf(wt, blo(dv.y), acc[2]); acc[3] = fmaf(wt, bhi(dv.y), acc[3]); \
    acc[4] = fmaf(wt, blo(dv.z), acc[4]); acc[5] = fmaf(wt, bhi(dv.z), acc[5]); \
    acc[6] = fmaf(wt, blo(dv.w), acc[6]); acc[7] = fmaf(wt, bhi(dv.w), acc[7]);

template <int NH>
__global__ __launch_bounds__(256) void agg4_fused(
    const u16* __restrict__ f, const float* __restrict__ al8,
    const int* __restrict__ row_ptr, const int* __restrict__ csr_src,
    const float* __restrict__ bias, const u16* __restrict__ resb,
    u16* __restrict__ outb, const float* __restrict__ qpost,
    float* __restrict__ alout, int n) {
    constexpr int NH2 = NH / 2;
    int wid = threadIdx.x >> 6, lane = threadIdx.x & 63;
    int i = blockIdx.x * 4 + wid;
    if (i >= n) return;
    int beg = row_ptr[i], end = row_ptr[i + 1];
    int h_st = lane >> 4;        // staging head
    int el = lane & 15;          // staging edge slot
    int half = lane >> 5;        // edge parity
    int c8 = (lane & 31) * 8;    // this lane's 8 channels
    int wsel = (lane & 24) << 1; // weight-shuffle source-lane base
    float ald_st = al8[(size_t)i * 8 + 4 + h_st];
    float acc[8] = {};
    float S = 0.f;
    for (int base = beg; base < end; base += 16) {
        int cnt = min(16, end - base);
        int idxv = csr_src[base + min(el, cnt - 1)];
        float av = al8[(size_t)idxv * 8 + h_st] + ald_st;
        av = av > 0.f ? av : 0.2f * av;
        float ex = __expf(fminf(av, 60.f));
        int e = 0;
        // main tier: 8 edges (4 per half-wave), 4 uint4 gathers in flight
        for (; e + 8 <= cnt; e += 8) {
            int s0 = __shfl(idxv, e + half);
            int s1 = __shfl(idxv, e + 2 + half);
            int s2 = __shfl(idxv, e + 4 + half);
            int s3 = __shfl(idxv, e + 6 + half);
            uint4 d0 = *(const uint4*)(f + (size_t)s0 * 256 + c8);
            uint4 d1 = *(const uint4*)(f + (size_t)s1 * 256 + c8);
            uint4 d2 = *(const uint4*)(f + (size_t)s2 * 256 + c8);
            uint4 d3 = *(const uint4*)(f + (size_t)s3 * 256 + c8);
            float w0 = __shfl(ex, wsel | (e + half));
            float w1 = __shfl(ex, wsel | (e + 2 + half));
            float w2 = __shfl(ex, wsel | (e + 4 + half));
            float w3 = __shfl(ex, wsel | (e + 6 + half));
            S += (w0 + w1) + (w2 + w3);
            ACC8(w0, d0);
            ACC8(w1, d1);
            ACC8(w2, d2);
            ACC8(w3, d3);
        }
        // mid tier: 4 edges, 2 gathers in flight
        for (; e + 4 <= cnt; e += 4) {
            int s0 = __shfl(idxv, e + half);
            int s1 = __shfl(idxv, e + 2 + half);
            uint4 d0 = *(const uint4*)(f + (size_t)s0 * 256 + c8);
            uint4 d1 = *(const uint4*)(f + (size_t)s1 * 256 + c8);
            float w0 = __shfl(ex, wsel | (e + half));
            float w1 = __shfl(ex, wsel | (e + 2 + half));
            S += w0 + w1;
            ACC8(w0, d0);
            ACC8(w1, d1);
        }
        // tail: pairs with clamp (<=3 edges left)
        for (; e < cnt; e += 2) {
            int ei = e + half;
            int eu = ei < cnt ? ei : e;
            int s = __shfl(idxv, eu);
            float w = __shfl(ex, wsel | eu);
            if (ei >= cnt) w = 0.f;
            S += w;
            uint4 d = *(const uint4*)(f + (size_t)s * 256 + c8);
            ACC8(w, d);
        }
    }
    #pragma unroll
    for (int k = 0; k < 8; k++) acc[k] += __shfl_xor(acc[k], 32);
    S += __shfl_xor(S, 32);
    // epilogue: BOTH halves now hold the full reduced row for their c8
    float inv = 1.f / (S + 1e-16f);
    float4 b0 = *(const float4*)(bias + c8);
    float4 b1 = *(const float4*)(bias + c8 + 4);
    float v[8];
    v[0] = acc[0] * inv + b0.x; v[1] = acc[1] * inv + b0.y;
    v[2] = acc[2] * inv + b0.z; v[3] = acc[3] * inv + b0.w;
    v[4] = acc[4] * inv + b1.x; v[5] = acc[5] * inv + b1.y;
    v[6] = acc[6] * inv + b1.z; v[7] = acc[7] * inv + b1.w;
    if (resb) {
        uint4 r = *(const uint4*)(resb + (size_t)i * 256 + c8);
        v[0] += blo(r.x); v[1] += bhi(r.x); v[2] += blo(r.y); v[3] += bhi(r.y);
        v[4] += blo(r.z); v[5] += bhi(r.z); v[6] += blo(r.w); v[7] += bhi(r.w);
    }
    #pragma unroll
    for (int k = 0; k < 8; k++) v[k] = v[k] > 0.f ? v[k] : (__expf(v[k]) - 1.f);  // ELU
    uint4 o;
    o.x = (unsigned)f2b(v[0]) | ((unsigned)f2b(v[1]) << 16);
    o.y = (unsigned)f2b(v[2]) | ((unsigned)f2b(v[3]) << 16);
    o.z = (unsigned)f2b(v[4]) | ((unsigned)f2b(v[5]) << 16);
    o.w = (unsigned)f2b(v[6]) | ((unsigned)f2b(v[7]) << 16);
    if (half == 0)
        *(uint4*)(outb + (size_t)i * 256 + c8) = o;
    if (NH > 0) {
        // next-layer logits from the bf16-ROUNDED row. Half 0 computes heads
        // [0,NH2), half 1 heads [NH2,NH); xor<32 reduce stays within a half.
        float rv[8];
        rv[0] = blo(o.x); rv[1] = bhi(o.x); rv[2] = blo(o.y); rv[3] = bhi(o.y);
        rv[4] = blo(o.z); rv[5] = bhi(o.z); rv[6] = blo(o.w); rv[7] = bhi(o.w);
        int hbase = half * NH2;
        float p[NH2 > 0 ? NH2 : 1];
        #pragma unroll
        for (int h = 0; h < NH2; h++) {
            const float* qp = qpost + (size_t)(hbase + h) * 256 + c8;
            float4 qa = *(const float4*)(qp);
            float4 qb = *(const float4*)(qp + 4);
            p[h] = rv[0] * qa.x + rv[1] * qa.y + rv[2] * qa.z + rv[3] * qa.w
                 + rv[4] * qb.x + rv[5] * qb.y + rv[6] * qb.z + rv[7] * qb.w;
        }
        #pragma unroll
        for (int ofs = 1; ofs <= 16; ofs <<= 1) {
            #pragma unroll
            for (int h = 0; h < NH2; h++) p[h] += __shfl_xor(p[h], ofs);
        }
        if ((lane & 31) == 0) {
            float* ap = alout + (size_t)i * NH + hbase;
            if (NH2 == 4) {
                *(float4*)ap = make_float4(p[0], p[1], p[2], p[3]);
            } else if (NH2 == 6) {
                if (half == 0) {
                    *(float4*)ap = make_float4(p[0], p[1], p[2], p[3]);
                    *(float2*)(ap + 4) = make_float2(p[4], p[5]);
                } else {
                    *(float2*)ap = make_float2(p[0], p[1]);
                    *(float4*)(ap + 2) = make_float4(p[2], p[3], p[4], p[5]);
                }
            } else {
                #pragma unroll
                for (int h = 0; h < NH2; h++) ap[h] = p[h];
            }
        }
    }
}

// ---------------- fused softmax+agg, layer 3 (6 heads): WAVE per node ----------------
// Ssum hoisted to a per-batch 16-lane shuffle reduction at staging.

__global__ __launch_bounds__(256) void aggS_fused(
    const u16* __restrict__ x, const float* __restrict__ al3,
    const int* __restrict__ row_ptr, const int* __restrict__ csr_src,
    u16* __restrict__ S, int node0, int count) {
    __shared__ int s_i[4][16];
    __shared__ float s_w[4][96];
    __shared__ float s_sum[4][6];
    int wid = threadIdx.x >> 6, lane = threadIdx.x & 63;
    int li = blockIdx.x * 4 + wid;
    if (li >= count) return;
    int i = node0 + li;
    int beg = row_ptr[i], end = row_ptr[i + 1];
    int c4 = lane * 4;
    int e16 = lane & 15;
    int hA = lane >> 4;            // heads 0-3 staging
    int hB = 4 + (lane >> 4);      // heads 4-5 staging (lanes 0-31)
    float aldA = al3[(size_t)i * 12 + 6 + hA];
    float aldB = (lane < 32) ? al3[(size_t)i * 12 + 6 + hB] : 0.f;
    float acc[6][4] = {};
    if (lane < 6) s_sum[wid][lane] = 0.f;
    for (int base = beg; base < end; base += 16) {
        int cnt = min(16, end - base);
        int idxe = csr_src[base + min(e16, cnt - 1)];
        if (lane < 16) s_i[wid][lane] = idxe;
        float vA = al3[(size_t)idxe * 12 + hA] + aldA;
        vA = vA > 0.f ? vA : 0.2f * vA;
        float exA = __expf(fminf(vA, 60.f));
        if (e16 < cnt) s_w[wid][e16 * 6 + hA] = exA;
        float exB = 0.f;
        if (lane < 32) {
            float vB = al3[(size_t)idxe * 12 + hB] + aldB;
            vB = vB > 0.f ? vB : 0.2f * vB;
            exB = __expf(fminf(vB, 60.f));
            if (e16 < cnt) s_w[wid][e16 * 6 + hB] = exB;
        }
        // per-batch head sums via 16-lane group reduction
        float sA = (e16 < cnt) ? exA : 0.f;
        sA += __shfl_xor(sA, 1); sA += __shfl_xor(sA, 2);
        sA += __shfl_xor(sA, 4); sA += __shfl_xor(sA, 8);
        float sB = (lane < 32 && e16 < cnt) ? exB : 0.f;
        sB += __shfl_xor(sB, 1); sB += __shfl_xor(sB, 2);
        sB += __shfl_xor(sB, 4); sB += __shfl_xor(sB, 8);
        if (e16 == 0) {
            s_sum[wid][hA] += sA;                    // lanes 0,16,32,48 -> heads 0-3
            if (lane < 32) s_sum[wid][hB] += sB;     // lanes 0,16     -> heads 4-5
        }
        // wave-coherent LDS (lockstep), no barrier
        int e = 0;
        for (; e + 4 <= cnt; e += 4) {
            int s0 = s_i[wid][e],     s1 = s_i[wid][e + 1];
            int s2 = s_i[wid][e + 2], s3 = s_i[wid][e + 3];
            uint2 d0 = *(const uint2*)(x + (size_t)s0 * 256 + c4);
            uint2 d1 = *(const uint2*)(x + (size_t)s1 * 256 + c4);
            uint2 d2 = *(const uint2*)(x + (size_t)s2 * 256 + c4);
            uint2 d3 = *(const uint2*)(x + (size_t)s3 * 256 + c4);
            float f00 = blo(d0.x), f01 = bhi(d0.x), f02 = blo(d0.y), f03 = bhi(d0.y);
            float f10 = blo(d1.x), f11 = bhi(d1.x), f12 = blo(d1.y), f13 = bhi(d1.y);
            float f20 = blo(d2.x), f21 = bhi(d2.x), f22 = blo(d2.y), f23 = bhi(d2.y);
            float f30 = blo(d3.x), f31 = bhi(d3.x), f32 = blo(d3.y), f33 = bhi(d3.y);
            #pragma unroll
            for (int hh = 0; hh < 6; hh++) {
                float w0 = s_w[wid][e * 6 + hh];
                float w1 = s_w[wid][(e + 1) * 6 + hh];
                float w2 = s_w[wid][(e + 2) * 6 + hh];
                float w3 = s_w[wid][(e + 3) * 6 + hh];
                acc[hh][0] = fmaf(w0, f00, acc[hh][0]);
                acc[hh][1] = fmaf(w0, f01, acc[hh][1]);
                acc[hh][2] = fmaf(w0, f02, acc[hh][2]);
                acc[hh][3] = fmaf(w0, f03, acc[hh][3]);
                acc[hh][0] = fmaf(w1, f10, acc[hh][0]);
                acc[hh][1] = fmaf(w1, f11, acc[hh][1]);
                acc[hh][2] = fmaf(w1, f12, acc[hh][2]);
                acc[hh][3] = fmaf(w1, f13, acc[hh][3]);
                acc[hh][0] = fmaf(w2, f20, acc[hh][0]);
                acc[hh][1] = fmaf(w2, f21, acc[hh][1]);
                acc[hh][2] = fmaf(w2, f22, acc[hh][2]);
                acc[hh][3] = fmaf(w2, f23, acc[hh][3]);
                acc[hh][0] = fmaf(w3, f30, acc[hh][0]);
                acc[hh][1] = fmaf(w3, f31, acc[hh][1]);
                acc[hh][2] = fmaf(w3, f32, acc[hh][2]);
                acc[hh][3] = fmaf(w3, f33, acc[hh][3]);
            }
        }
        for (; e < cnt; e++) {
            int s = s_i[wid][e];
            uint2 d = *(const uint2*)(x + (size_t)s * 256 + c4);
            float v0 = blo(d.x), v1 = bhi(d.x), v2 = blo(d.y), v3 = bhi(d.y);
            #pragma unroll
            for (int hh = 0; hh < 6; hh++) {
                float w = s_w[wid][e * 6 + hh];
                acc[hh][0] = fmaf(w, v0, acc[hh][0]);
                acc[hh][1] = fmaf(w, v1, acc[hh][1]);
                acc[hh][2] = fmaf(w, v2, acc[hh][2]);
                acc[hh][3] = fmaf(w, v3, acc[hh][3]);
            }
        }
    }
    #pragma unroll
    for (int hh = 0; hh < 6; hh++) {
        float inv = 1.f / (6.f * (s_sum[wid][hh] + 1e-16f));
        ushort4 o;
        o.x = f2b(acc[hh][0] * inv);
        o.y = f2b(acc[hh][1] * inv);
        o.z = f2b(acc[hh][2] * inv);
        o.w = f2b(acc[hh][3] * inv);
        *(ushort4*)(S + (size_t)li * 1536 + hh * 256 + c4) = o;
    }
}

// ---------------- host ----------------

extern "C" void kernel_launch(void* const* d_in, const int* in_sizes, int n_in,
                              void* d_out, int out_size, void* d_ws, size_t ws_size,
                              hipStream_t stream) {
    const float* x      = (const float*)d_in[0];
    const int*   src    = (const int*)d_in[1];
    const int*   dst    = (const int*)d_in[2];
    const float* W1     = (const float*)d_in[3];
    const float* a1_src = (const float*)d_in[4];
    const float* a1_dst = (const float*)d_in[5];
    const float* b1     = (const float*)d_in[6];
    const float* W2     = (const float*)d_in[7];
    const float* a2_src = (const float*)d_in[8];
    const float* a2_dst = (const float*)d_in[9];
    const float* b2     = (const float*)d_in[10];
    const float* Wres2  = (const float*)d_in[11];
    const float* W3     = (const float*)d_in[12];
    const float* a3_src = (const float*)d_in[13];
    const float* a3_dst = (const float*)d_in[14];
    const float* b3     = (const float*)d_in[15];
    float* out = (float*)d_out;

    const int N = NODES, E = EDGES;
    const int EN = E + N;
    const int NB = (N + 255) / 256;  // 196
    const int NRT = MPAD / 128;      // 391 row tiles

    char* p = (char*)d_ws;
    auto alloc = [&](size_t bytes) -> char* {
        char* r = p;
        p += (bytes + 511) & ~(size_t)511;
        return r;
    };
    // persistent
    int*   row_ptr = (int*)alloc((size_t)(N + 1) * sizeof(int));
    int*   cursor  = (int*)alloc((size_t)N * sizeof(int));
    int*   deg     = (int*)alloc((size_t)N * sizeof(int));
    int*   bsum    = (int*)alloc(256 * sizeof(int));
    int*   csr_src = (int*)alloc((size_t)EN * sizeof(int));
    float* alA     = (float*)alloc((size_t)N * 8 * sizeof(float));
    float* alB     = (float*)alloc((size_t)N * 8 * sizeof(float));
    float* al3     = (float*)alloc((size_t)N * 12 * sizeof(float));
    float* q1t     = (float*)alloc((size_t)8 * 128 * sizeof(float));
    float* q2t     = (float*)alloc((size_t)8 * 256 * sizeof(float));
    float* cm      = (float*)alloc((size_t)12 * 256 * sizeof(float));
    u16*   WT1     = (u16*)alloc((size_t)256 * 128 * sizeof(u16));
    u16*   WT2     = (u16*)alloc((size_t)512 * 256 * sizeof(u16));
    u16*   W3sT    = (u16*)alloc((size_t)128 * 1536 * sizeof(u16));
    u16*   o2b     = (u16*)alloc((size_t)MPAD * 256 * sizeof(u16));
    // region2 (phase-overlaid)
    const size_t A2B_B  = (size_t)MPAD * 256 * sizeof(u16);
    const size_t F1B_B  = (size_t)N * 256 * sizeof(u16);
    const size_t RESB_B = (size_t)N * 256 * sizeof(u16);
    const size_t S_B    = (size_t)C0 * 1536 * sizeof(u16);
    size_t r2_bytes = A2B_B + F1B_B + RESB_B;
    if (S_B > r2_bytes) r2_bytes = S_B;
    char* r2 = alloc(r2_bytes + 1024);
    u16* A2b  = (u16*)r2;                        // layer-1 out bf16 [MPAD,256]
    u16* f1b  = (u16*)(r2 + A2B_B);              // layer feat bf16 [N,256]
    u16* resb = (u16*)(r2 + A2B_B + F1B_B);      // layer-2 residual bf16 [N,256]
    u16* A2a  = (u16*)(r2 + A2B_B + F1B_B);      // x bf16 [MPAD,128] (dead before resb)
    u16* Sb   = (u16*)r2;                        // S chunk bf16 [C0,1536] (layer 3)
    (void)ws_size; (void)n_in; (void)in_sizes; (void)out_size;

    // --- CSR build (deg zeroed by memset; hist counts edges + self-loops) ---
    hipMemsetAsync(deg, 0, (size_t)N * sizeof(int), stream);
    hist_kernel<<<(EN + 255) / 256, 256, 0, stream>>>(dst, deg, E, N);
    deg_bsum_kernel<<<NB, 256, 0, stream>>>(deg, bsum, N);
    bsum_scan_kernel<<<1, 256, 0, stream>>>(bsum, row_ptr, NB, N);
    deg_scan_kernel<<<NB, 256, 0, stream>>>(deg, bsum, row_ptr, cursor, N);
    scatter_kernel<<<(EN + 255) / 256, 256, 0, stream>>>(src, dst, E, N, cursor, csr_src);

    int nwb = (N + 3) / 4;

    // --- all weight prep in one launch ---
    prep_weights<<<(PREP_TOTAL + 255) / 256, 256, 0, stream>>>(
        W1, W2, Wres2, W3, a1_src, a1_dst, a2_src, a2_dst, a3_src, a3_dst,
        WT1, WT2, W3sT, q1t, q2t, cm);

    // --- layer 1: 128 -> 4x64 concat, ELU ---
    convx_al1<<<nwb, 256, 0, stream>>>(x, q1t, A2a, alA, N);
    {
        int nblk = 8 * ((NRT + 7) / 8) * 2;   // XCD-swizzled 1D grid, NT=2
        gemm_mfma_kernel<<<nblk, 256, 0, stream>>>(A2a, WT1, f1b, nullptr,
                                                   N, 128, 256, 9999, 2, NRT);
    }
    // agg + fused layer-2 logits (alB = rounded_out . q2t)
    agg4_fused<8><<<nwb, 256, 0, stream>>>(f1b, alA, row_ptr, csr_src, b1, nullptr,
                                           A2b, q2t, alB, N);

    // --- layer 2: 256 -> 4x64 concat + residual (one 512-wide GEMM), ELU ---
    {
        int nblk = 8 * ((NRT + 7) / 8) * 4;   // NT=4
        gemm_mfma_kernel<<<nblk, 256, 0, stream>>>(A2b, WT2, f1b, resb,
                                                   N, 256, 256, 256, 4, NRT);
    }
    // agg + fused layer-3 logits (al3 = rounded_out . cm)
    agg4_fused<12><<<nwb, 256, 0, stream>>>(f1b, alB, row_ptr, csr_src, b2, resb,
                                            o2b, cm, al3, N);

    // --- layer 3: fused softmax+input-space agg -> skinny GEMM ---
    {
        aggS_fused<<<(C0 + 3) / 4, 256, 0, stream>>>(o2b, al3, row_ptr, csr_src, Sb, 0, C0);
        gemm_skinny64<<<(C0 + 63) / 64, 256, 0, stream>>>(Sb, W3sT, out, b3, C0);
        aggS_fused<<<(C1 + 3) / 4, 256, 0, stream>>>(o2b, al3, row_ptr, csr_src, Sb, C0, C1);
        gemm_skinny64<<<(C1 + 63) / 64, 256, 0, stream>>>(Sb, W3sT, out + (size_t)C0 * 121, b3, C1);
    }
}

// Round 12
// 576.763 us; speedup vs baseline: 1.0563x; 1.0395x over previous
//
#include <hip/hip_runtime.h>
#include <hip/hip_bf16.h>

// PPI GAT, 3 layers. N=50000, E=800000 (+N self loops), avg degree ~17.
// R17: 598-599 plateau confirmed (R16 CSR cleanup: neutral). agg4 at its
// gather floor, GEMMs at best measured form. Last structural slack: layer-3
// chunking (S buffer half-N) forces aggS0->skinny0->aggS1->skinny1 serial
// chain. If ws_size permits full-N S (153.6MB), run ONE aggS + ONE skinny —
// two fewer kernel tails + one fewer dependency stall. Runtime-gated on
// ws_size with fallback to the proven chunked path (zero risk).

#define NODES 50000
#define EDGES 800000
#define MPAD  50048            // ceil(N/128)*128
#define C0    25088            // layer-3 chunk-0 rows
#define C1    24912            // layer-3 chunk-1 rows

typedef unsigned short u16;
typedef __attribute__((ext_vector_type(8))) short bf16x8;
typedef __attribute__((ext_vector_type(4))) float f32x4;

__device__ __forceinline__ float bf16f(u16 r) {
    return __uint_as_float(((unsigned)r) << 16);
}
__device__ __forceinline__ u16 f2b(float v) {
    __hip_bfloat16 b = __float2bfloat16(v);
    return *(u16*)&b;
}
__device__ __forceinline__ float blo(unsigned d) { return __uint_as_float(d << 16); }
__device__ __forceinline__ float bhi(unsigned d) { return __uint_as_float(d & 0xffff0000u); }

// ---------------- CSR build ----------------

// deg pre-zeroed by hipMemsetAsync; counts edges AND self-loops in one pass.
__global__ void hist_kernel(const int* __restrict__ dst, int* __restrict__ deg,
                            int E, int n) {
    int e = blockIdx.x * blockDim.x + threadIdx.x;
    if (e < E) atomicAdd(&deg[dst[e]], 1);
    else if (e < E + n) atomicAdd(&deg[e - E], 1);  // self-loop
}

__global__ void deg_bsum_kernel(const int* __restrict__ deg, int* __restrict__ bsum, int n) {
    int tid = threadIdx.x, lane = tid & 63, wid = tid >> 6;
    int i = blockIdx.x * 256 + tid;
    int v = (i < n) ? deg[i] : 0;
    #pragma unroll
    for (int ofs = 32; ofs > 0; ofs >>= 1) v += __shfl_down(v, ofs);
    __shared__ int sp[4];
    if (lane == 0) sp[wid] = v;
    __syncthreads();
    if (tid == 0) bsum[blockIdx.x] = sp[0] + sp[1] + sp[2] + sp[3];
}

__global__ void bsum_scan_kernel(int* __restrict__ bsum, int* __restrict__ row_ptr,
                                 int nb, int n) {
    int tid = threadIdx.x, lane = tid & 63, wid = tid >> 6;
    int v = (tid < nb) ? bsum[tid] : 0;
    int incl = v;
    #pragma unroll
    for (int ofs = 1; ofs < 64; ofs <<= 1) {
        int t = __shfl_up(incl, ofs);
        if (lane >= ofs) incl += t;
    }
    __shared__ int sp[4];
    if (lane == 63) sp[wid] = incl;
    __syncthreads();
    int add = 0;
    for (int k = 0; k < wid; k++) add += sp[k];
    int excl = incl - v + add;
    if (tid < nb) bsum[tid] = excl;
    if (tid == nb - 1) row_ptr[n] = excl + v;
}

__global__ void deg_scan_kernel(const int* __restrict__ deg, const int* __restrict__ bofs,
                                int* __restrict__ row_ptr, int* __restrict__ cursor, int n) {
    int tid = threadIdx.x, lane = tid & 63, wid = tid >> 6;
    int i = blockIdx.x * 256 + tid;
    int v = (i < n) ? deg[i] : 0;
    int incl = v;
    #pragma unroll
    for (int ofs = 1; ofs < 64; ofs <<= 1) {
        int t = __shfl_up(incl, ofs);
        if (lane >= ofs) incl += t;
    }
    __shared__ int sp[4];
    if (lane == 63) sp[wid] = incl;
    __syncthreads();
    int add = bofs[blockIdx.x];
    for (int k = 0; k < wid; k++) add += sp[k];
    int excl = incl - v + add;
    if (i < n) { row_ptr[i] = excl; cursor[i] = excl; }
}

__global__ void scatter_kernel(const int* __restrict__ src, const int* __restrict__ dst,
                               int E, int n, int* __restrict__ cursor, int* __restrict__ csr_src) {
    int e = blockIdx.x * blockDim.x + threadIdx.x;
    if (e < E) {
        int d = dst[e];
        int p = atomicAdd(&cursor[d], 1);
        csr_src[p] = src[e];
    } else if (e < E + n) {
        int i = e - E;
        int p = atomicAdd(&cursor[i], 1);
        csr_src[p] = i;  // self-loop
    }
}

// ---------------- prep: all weight converts + q-vectors, one launch ----------------

__global__ void prep_weights(
    const float* __restrict__ W1, const float* __restrict__ W2,
    const float* __restrict__ Wres2, const float* __restrict__ W3,
    const float* __restrict__ a1s, const float* __restrict__ a1d,
    const float* __restrict__ a2s, const float* __restrict__ a2d,
    const float* __restrict__ a3s, const float* __restrict__ a3d,
    u16* __restrict__ WT1, u16* __restrict__ WT2, u16* __restrict__ W3sT,
    float* __restrict__ q1t, float* __restrict__ q2t, float* __restrict__ cm) {
    int idx = blockIdx.x * 256 + threadIdx.x;
    if (idx < 32768) {                        // WT1
        int n = idx >> 7, k = idx & 127;
        WT1[idx] = f2b(W1[(size_t)k * 256 + n]);
    } else if ((idx -= 32768) < 131072) {     // WT2 = [W2 | Wres2]
        int n = idx >> 8, k = idx & 255;
        float v = (n < 256) ? W2[(size_t)k * 256 + n] : Wres2[(size_t)k * 256 + (n - 256)];
        WT2[idx] = f2b(v);
    } else if ((idx -= 131072) < 196608) {    // W3sT
        int n = idx / 1536, q = idx % 1536;
        int h = q >> 8, k = q & 255;
        W3sT[idx] = f2b((n < 121) ? W3[(size_t)k * 726 + h * 121 + n] : 0.f);
    } else if ((idx -= 196608) < 1024) {      // q1t
        int h = idx >> 7, k = idx & 127;
        int hh = h & 3;
        const float* a = (h < 4) ? a1s : a1d;
        float v = 0.f;
        for (int c = 0; c < 64; c++) v += W1[(size_t)k * 256 + hh * 64 + c] * a[hh * 64 + c];
        q1t[idx] = v;
    } else if ((idx -= 1024) < 2048) {        // q2t [8][256]
        int h = idx >> 8, k = idx & 255;
        int hh = h & 3;
        const float* a = (h < 4) ? a2s : a2d;
        float v = 0.f;
        for (int c = 0; c < 64; c++) v += W2[(size_t)k * 256 + hh * 64 + c] * a[hh * 64 + c];
        q2t[idx] = v;
    } else if ((idx -= 2048) < 3072) {        // cm [12][256]
        int o = idx >> 8, k = idx & 255;
        int h = (o < 6) ? o : o - 6;
        const float* a = (o < 6) ? a3s : a3d;
        float v = 0.f;
        for (int c = 0; c < 121; c++) v += W3[(size_t)k * 726 + h * 121 + c] * a[h * 121 + c];
        cm[idx] = v;
    }
}
#define PREP_TOTAL (32768 + 131072 + 196608 + 1024 + 2048 + 3072)

// ---------------- convx + layer-1 logits: wave per node ----------------

__global__ __launch_bounds__(256) void convx_al1(
    const float* __restrict__ x, const float* __restrict__ q1t,
    u16* __restrict__ A2a, float* __restrict__ alA, int n) {
    int wid = threadIdx.x >> 6, lane = threadIdx.x & 63;
    int i = blockIdx.x * 4 + wid;
    if (i >= n) return;
    float2 xv = *(const float2*)(x + (size_t)i * 128 + lane * 2);
    ushort2 o;
    o.x = f2b(xv.x); o.y = f2b(xv.y);
    *(ushort2*)(A2a + (size_t)i * 128 + lane * 2) = o;
    float p[8];
    #pragma unroll
    for (int h = 0; h < 8; h++) {
        float2 q = *(const float2*)(q1t + h * 128 + lane * 2);
        p[h] = xv.x * q.x + xv.y * q.y;
    }
    #pragma unroll
    for (int ofs = 1; ofs <= 32; ofs <<= 1) {
        #pragma unroll
        for (int h = 0; h < 8; h++) p[h] += __shfl_xor(p[h], ofs);
    }
    if (lane == 0) {
        *(float4*)(alA + (size_t)i * 8)     = make_float4(p[0], p[1], p[2], p[3]);
        *(float4*)(alA + (size_t)i * 8 + 4) = make_float4(p[4], p[5], p[6], p[7]);
    }
}

// ---------------- bf16 MFMA GEMM: C = A @ B^T, bf16 out, col split ----------------
// 1D grid, XCD swizzle (x=b&7): per-XCD consecutive blocks cover all NT
// col-tiles of one A row-panel -> panel lives in exactly one L2. Register
// double-buffer: K-tile t+1 prefetched into regs during tile t's MFMAs.
// LDS-transpose epilogue with coalesced uint4 stores.

__global__ __launch_bounds__(256) void gemm_mfma_kernel(
    const u16* __restrict__ A, const u16* __restrict__ B,
    u16* __restrict__ Cb, u16* __restrict__ Cb2,
    int M, int K2, int ldc, int split, int NT, int nrt) {
    __shared__ __align__(16) u16 smem[2][128][40];
    #define As smem[0]
    #define Bs smem[1]
    int b = blockIdx.x;
    int xcd = b & 7, q = b >> 3;
    int ct = q % NT, rb = q / NT;
    int rt = rb * 8 + xcd;
    if (rt >= nrt) return;
    int bm = rt * 128, bn = ct * 128;

    int tid = threadIdx.x;
    int lane = tid & 63;
    int wv = tid >> 6;
    int quad = lane >> 4, lm = lane & 15;
    int wm = (wv & 1) * 64, wn = (wv >> 1) * 64;

    int lrow0 = tid >> 2, lseg0 = (tid & 3) * 8;
    int lrow1 = (tid + 256) >> 2, lseg1 = ((tid + 256) & 3) * 8;
    const u16* Ap0 = A + (size_t)(bm + lrow0) * K2 + lseg0;
    const u16* Ap1 = A + (size_t)(bm + lrow1) * K2 + lseg1;
    const u16* Bp0 = B + (size_t)(bn + lrow0) * K2 + lseg0;
    const u16* Bp1 = B + (size_t)(bn + lrow1) * K2 + lseg1;

    f32x4 zero = {0.f, 0.f, 0.f, 0.f};
    f32x4 acc[4][4];
    #pragma unroll
    for (int i = 0; i < 4; i++)
        #pragma unroll
        for (int j = 0; j < 4; j++) acc[i][j] = zero;

    // prologue: prefetch tile 0
    uint4 pa0 = *(const uint4*)(Ap0), pa1 = *(const uint4*)(Ap1);
    uint4 pb0 = *(const uint4*)(Bp0), pb1 = *(const uint4*)(Bp1);

    for (int k0 = 0; k0 < K2; k0 += 32) {
        *(uint4*)&As[lrow0][lseg0] = pa0;
        *(uint4*)&As[lrow1][lseg1] = pa1;
        *(uint4*)&Bs[lrow0][lseg0] = pb0;
        *(uint4*)&Bs[lrow1][lseg1] = pb1;
        __syncthreads();
        bool more = (k0 + 32) < K2;
        if (more) {
            pa0 = *(const uint4*)(Ap0 + k0 + 32);
            pa1 = *(const uint4*)(Ap1 + k0 + 32);
            pb0 = *(const uint4*)(Bp0 + k0 + 32);
            pb1 = *(const uint4*)(Bp1 + k0 + 32);
        }
        bf16x8 af[4], bfr[4];
        #pragma unroll
        for (int i = 0; i < 4; i++) af[i] = *(const bf16x8*)&As[wm + i * 16 + lm][quad * 8];
        #pragma unroll
        for (int j = 0; j < 4; j++) bfr[j] = *(const bf16x8*)&Bs[wn + j * 16 + lm][quad * 8];
        #pragma unroll
        for (int i = 0; i < 4; i++)
            #pragma unroll
            for (int j = 0; j < 4; j++)
                acc[i][j] = __builtin_amdgcn_mfma_f32_16x16x32_bf16(af[i], bfr[j], acc[i][j], 0, 0, 0);
        __syncthreads();
    }

    // epilogue: LDS transpose, two 64-row halves, coalesced uint4 stores.
    // C/D layout: col = lane&15, row = quad*4 + reg.
    u16* Cp = (bn < split) ? (Cb + bn) : (Cb2 + (bn - split));
    u16 (*St)[136] = (u16(*)[136])&smem[0][0][0];  // 64 x 136 u16 = 17408B
    #pragma unroll
    for (int halfrow = 0; halfrow < 2; ++halfrow) {
        __syncthreads();
        if ((wv & 1) == halfrow) {
            #pragma unroll
            for (int i = 0; i < 4; i++) {
                int lr = i * 16 + quad * 4;
                #pragma unroll
                for (int j = 0; j < 4; j++) {
                    int lc = wn + j * 16 + lm;
                    #pragma unroll
                    for (int r = 0; r < 4; r++)
                        St[lr + r][lc] = f2b(acc[i][j][r]);
                }
            }
        }
        __syncthreads();
        #pragma unroll
        for (int it = 0; it < 4; ++it) {
            int idx = tid + it * 256;           // 0..1023
            int row = idx >> 4, seg = idx & 15; // 64 rows x 16 uint4
            int grow = bm + halfrow * 64 + row;
            if (grow < M)
                *(uint4*)(Cp + (size_t)grow * ldc + seg * 8) = *(const uint4*)&St[row][seg * 8];
        }
    }
    #undef As
    #undef Bs
}

// ---------------- skinny GEMM (layer 3): C[count,121] = A[count,1536] @ B[128,1536]^T ----
// register double-buffer on the 48-step K loop.

__global__ __launch_bounds__(256) void gemm_skinny64(
    const u16* __restrict__ A, const u16* __restrict__ B,
    float* __restrict__ C, const float* __restrict__ bias, int count) {
    __shared__ __align__(16) u16 As[64][40];
    __shared__ __align__(16) u16 Bs[128][40];
    int tid = threadIdx.x, lane = tid & 63, wv = tid >> 6;
    int quad = lane >> 4, lm = lane & 15;
    int bm = blockIdx.x * 64;
    int mrow = (wv >> 1) * 32, ncol = (wv & 1) * 64;
    int ar = bm + (tid >> 2);
    if (ar >= count) ar = count - 1;
    const u16* Ap = A + (size_t)ar * 1536 + (tid & 3) * 8;
    int brow0 = tid >> 2, bseg0 = (tid & 3) * 8;
    int brow1 = (tid + 256) >> 2, bseg1 = ((tid + 256) & 3) * 8;
    const u16* Bp0 = B + (size_t)brow0 * 1536 + bseg0;
    const u16* Bp1 = B + (size_t)brow1 * 1536 + bseg1;

    f32x4 zero = {0.f, 0.f, 0.f, 0.f};
    f32x4 acc[2][4];
    #pragma unroll
    for (int i = 0; i < 2; i++)
        #pragma unroll
        for (int j = 0; j < 4; j++) acc[i][j] = zero;

    uint4 pa = *(const uint4*)(Ap);
    uint4 pb0 = *(const uint4*)(Bp0);
    uint4 pb1 = *(const uint4*)(Bp1);

    for (int k0 = 0; k0 < 1536; k0 += 32) {
        *(uint4*)&As[tid >> 2][(tid & 3) * 8] = pa;
        *(uint4*)&Bs[brow0][bseg0] = pb0;
        *(uint4*)&Bs[brow1][bseg1] = pb1;
        __syncthreads();
        bool more = (k0 + 32) < 1536;
        if (more) {
            pa  = *(const uint4*)(Ap + k0 + 32);
            pb0 = *(const uint4*)(Bp0 + k0 + 32);
            pb1 = *(const uint4*)(Bp1 + k0 + 32);
        }
        bf16x8 af[2], bfr[4];
        #pragma unroll
        for (int i = 0; i < 2; i++) af[i] = *(const bf16x8*)&As[mrow + i * 16 + lm][quad * 8];
        #pragma unroll
        for (int j = 0; j < 4; j++) bfr[j] = *(const bf16x8*)&Bs[ncol + j * 16 + lm][quad * 8];
        #pragma unroll
        for (int i = 0; i < 2; i++)
            #pragma unroll
            for (int j = 0; j < 4; j++)
                acc[i][j] = __builtin_amdgcn_mfma_f32_16x16x32_bf16(af[i], bfr[j], acc[i][j], 0, 0, 0);
        __syncthreads();
    }

    #pragma unroll
    for (int i = 0; i < 2; i++) {
        #pragma unroll
        for (int j = 0; j < 4; j++) {
            int col = ncol + j * 16 + lm;
            if (col >= 121) continue;
            int row_base = bm + mrow + i * 16 + quad * 4;
            #pragma unroll
            for (int r = 0; r < 4; r++) {
                int row = row_base + r;
                if (row >= count) continue;
                float v = acc[i][j][r] + bias[col];
                v = 1.f / (1.f + __expf(-v));
                C[(size_t)row * 121 + col] = v;
            }
        }
    }
}

// ---------------- fused softmax+agg + NEXT-LAYER LOGITS, layers 1&2 ----------------
// al8 layout: [i][0..3]=src logits, [i][4..7]=dst logits.
// 8-edge main tier (4 uint4 gathers in flight) + 4-edge mid tier + pair tail.
// NH>0 epilogue (split-half): after the xor(32) reduce both halves hold the
// full row; half 0 computes logit heads [0,NH/2), half 1 [NH/2,NH).
// Macro params wt/dv (NOT w/d): .w field access must not be captured.

#define ACC8(wt, dv) \
    acc[0] = fmaf(wt, blo(dv.x), acc[0]); acc[1] = fmaf(wt, bhi(dv.x), acc[1]); \
    acc[2] = fmaf(wt, blo(dv.y), acc[2]); acc[3] = fmaf(wt, bhi(dv.y), acc[3]); \
    acc[4] = fmaf(wt, blo(dv.z), acc[4]); acc[5] = fmaf(wt, bhi(dv.z), acc[5]); \
    acc[6] = fmaf(wt, blo(dv.w), acc[6]); acc[7] = fmaf(wt, bhi(dv.w), acc[7]);

template <int NH>
__global__ __launch_bounds__(256) void agg4_fused(
    const u16* __restrict__ f, const float* __restrict__ al8,
    const int* __restrict__ row_ptr, const int* __restrict__ csr_src,
    const float* __restrict__ bias, const u16* __restrict__ resb,
    u16* __restrict__ outb, const float* __restrict__ qpost,
    float* __restrict__ alout, int n) {
    constexpr int NH2 = NH / 2;
    int wid = threadIdx.x >> 6, lane = threadIdx.x & 63;
    int i = blockIdx.x * 4 + wid;
    if (i >= n) return;
    int beg = row_ptr[i], end = row_ptr[i + 1];
    int h_st = lane >> 4;        // staging head
    int el = lane & 15;          // staging edge slot
    int half = lane >> 5;        // edge parity
    int c8 = (lane & 31) * 8;    // this lane's 8 channels
    int wsel = (lane & 24) << 1; // weight-shuffle source-lane base
    float ald_st = al8[(size_t)i * 8 + 4 + h_st];
    float acc[8] = {};
    float S = 0.f;
    for (int base = beg; base < end; base += 16) {
        int cnt = min(16, end - base);
        int idxv = csr_src[base + min(el, cnt - 1)];
        float av = al8[(size_t)idxv * 8 + h_st] + ald_st;
        av = av > 0.f ? av : 0.2f * av;
        float ex = __expf(fminf(av, 60.f));
        int e = 0;
        // main tier: 8 edges (4 per half-wave), 4 uint4 gathers in flight
        for (; e + 8 <= cnt; e += 8) {
            int s0 = __shfl(idxv, e + half);
            int s1 = __shfl(idxv, e + 2 + half);
            int s2 = __shfl(idxv, e + 4 + half);
            int s3 = __shfl(idxv, e + 6 + half);
            uint4 d0 = *(const uint4*)(f + (size_t)s0 * 256 + c8);
            uint4 d1 = *(const uint4*)(f + (size_t)s1 * 256 + c8);
            uint4 d2 = *(const uint4*)(f + (size_t)s2 * 256 + c8);
            uint4 d3 = *(const uint4*)(f + (size_t)s3 * 256 + c8);
            float w0 = __shfl(ex, wsel | (e + half));
            float w1 = __shfl(ex, wsel | (e + 2 + half));
            float w2 = __shfl(ex, wsel | (e + 4 + half));
            float w3 = __shfl(ex, wsel | (e + 6 + half));
            S += (w0 + w1) + (w2 + w3);
            ACC8(w0, d0);
            ACC8(w1, d1);
            ACC8(w2, d2);
            ACC8(w3, d3);
        }
        // mid tier: 4 edges, 2 gathers in flight
        for (; e + 4 <= cnt; e += 4) {
            int s0 = __shfl(idxv, e + half);
            int s1 = __shfl(idxv, e + 2 + half);
            uint4 d0 = *(const uint4*)(f + (size_t)s0 * 256 + c8);
            uint4 d1 = *(const uint4*)(f + (size_t)s1 * 256 + c8);
            float w0 = __shfl(ex, wsel | (e + half));
            float w1 = __shfl(ex, wsel | (e + 2 + half));
            S += w0 + w1;
            ACC8(w0, d0);
            ACC8(w1, d1);
        }
        // tail: pairs with clamp (<=3 edges left)
        for (; e < cnt; e += 2) {
            int ei = e + half;
            int eu = ei < cnt ? ei : e;
            int s = __shfl(idxv, eu);
            float w = __shfl(ex, wsel | eu);
            if (ei >= cnt) w = 0.f;
            S += w;
            uint4 d = *(const uint4*)(f + (size_t)s * 256 + c8);
            ACC8(w, d);
        }
    }
    #pragma unroll
    for (int k = 0; k < 8; k++) acc[k] += __shfl_xor(acc[k], 32);
    S += __shfl_xor(S, 32);
    // epilogue: BOTH halves now hold the full reduced row for their c8
    float inv = 1.f / (S + 1e-16f);
    float4 b0 = *(const float4*)(bias + c8);
    float4 b1 = *(const float4*)(bias + c8 + 4);
    float v[8];
    v[0] = acc[0] * inv + b0.x; v[1] = acc[1] * inv + b0.y;
    v[2] = acc[2] * inv + b0.z; v[3] = acc[3] * inv + b0.w;
    v[4] = acc[4] * inv + b1.x; v[5] = acc[5] * inv + b1.y;
    v[6] = acc[6] * inv + b1.z; v[7] = acc[7] * inv + b1.w;
    if (resb) {
        uint4 r = *(const uint4*)(resb + (size_t)i * 256 + c8);
        v[0] += blo(r.x); v[1] += bhi(r.x); v[2] += blo(r.y); v[3] += bhi(r.y);
        v[4] += blo(r.z); v[5] += bhi(r.z); v[6] += blo(r.w); v[7] += bhi(r.w);
    }
    #pragma unroll
    for (int k = 0; k < 8; k++) v[k] = v[k] > 0.f ? v[k] : (__expf(v[k]) - 1.f);  // ELU
    uint4 o;
    o.x = (unsigned)f2b(v[0]) | ((unsigned)f2b(v[1]) << 16);
    o.y = (unsigned)f2b(v[2]) | ((unsigned)f2b(v[3]) << 16);
    o.z = (unsigned)f2b(v[4]) | ((unsigned)f2b(v[5]) << 16);
    o.w = (unsigned)f2b(v[6]) | ((unsigned)f2b(v[7]) << 16);
    if (half == 0)
        *(uint4*)(outb + (size_t)i * 256 + c8) = o;
    if (NH > 0) {
        // next-layer logits from the bf16-ROUNDED row. Half 0 computes heads
        // [0,NH2), half 1 heads [NH2,NH); xor<32 reduce stays within a half.
        float rv[8];
        rv[0] = blo(o.x); rv[1] = bhi(o.x); rv[2] = blo(o.y); rv[3] = bhi(o.y);
        rv[4] = blo(o.z); rv[5] = bhi(o.z); rv[6] = blo(o.w); rv[7] = bhi(o.w);
        int hbase = half * NH2;
        float p[NH2 > 0 ? NH2 : 1];
        #pragma unroll
        for (int h = 0; h < NH2; h++) {
            const float* qp = qpost + (size_t)(hbase + h) * 256 + c8;
            float4 qa = *(const float4*)(qp);
            float4 qb = *(const float4*)(qp + 4);
            p[h] = rv[0] * qa.x + rv[1] * qa.y + rv[2] * qa.z + rv[3] * qa.w
                 + rv[4] * qb.x + rv[5] * qb.y + rv[6] * qb.z + rv[7] * qb.w;
        }
        #pragma unroll
        for (int ofs = 1; ofs <= 16; ofs <<= 1) {
            #pragma unroll
            for (int h = 0; h < NH2; h++) p[h] += __shfl_xor(p[h], ofs);
        }
        if ((lane & 31) == 0) {
            float* ap = alout + (size_t)i * NH + hbase;
            if (NH2 == 4) {
                *(float4*)ap = make_float4(p[0], p[1], p[2], p[3]);
            } else if (NH2 == 6) {
                if (half == 0) {
                    *(float4*)ap = make_float4(p[0], p[1], p[2], p[3]);
                    *(float2*)(ap + 4) = make_float2(p[4], p[5]);
                } else {
                    *(float2*)ap = make_float2(p[0], p[1]);
                    *(float4*)(ap + 2) = make_float4(p[2], p[3], p[4], p[5]);
                }
            } else {
                #pragma unroll
                for (int h = 0; h < NH2; h++) ap[h] = p[h];
            }
        }
    }
}

// ---------------- fused softmax+agg, layer 3 (6 heads): WAVE per node ----------------
// Ssum hoisted to a per-batch 16-lane shuffle reduction at staging.

__global__ __launch_bounds__(256) void aggS_fused(
    const u16* __restrict__ x, const float* __restrict__ al3,
    const int* __restrict__ row_ptr, const int* __restrict__ csr_src,
    u16* __restrict__ S, int node0, int count) {
    __shared__ int s_i[4][16];
    __shared__ float s_w[4][96];
    __shared__ float s_sum[4][6];
    int wid = threadIdx.x >> 6, lane = threadIdx.x & 63;
    int li = blockIdx.x * 4 + wid;
    if (li >= count) return;
    int i = node0 + li;
    int beg = row_ptr[i], end = row_ptr[i + 1];
    int c4 = lane * 4;
    int e16 = lane & 15;
    int hA = lane >> 4;            // heads 0-3 staging
    int hB = 4 + (lane >> 4);      // heads 4-5 staging (lanes 0-31)
    float aldA = al3[(size_t)i * 12 + 6 + hA];
    float aldB = (lane < 32) ? al3[(size_t)i * 12 + 6 + hB] : 0.f;
    float acc[6][4] = {};
    if (lane < 6) s_sum[wid][lane] = 0.f;
    for (int base = beg; base < end; base += 16) {
        int cnt = min(16, end - base);
        int idxe = csr_src[base + min(e16, cnt - 1)];
        if (lane < 16) s_i[wid][lane] = idxe;
        float vA = al3[(size_t)idxe * 12 + hA] + aldA;
        vA = vA > 0.f ? vA : 0.2f * vA;
        float exA = __expf(fminf(vA, 60.f));
        if (e16 < cnt) s_w[wid][e16 * 6 + hA] = exA;
        float exB = 0.f;
        if (lane < 32) {
            float vB = al3[(size_t)idxe * 12 + hB] + aldB;
            vB = vB > 0.f ? vB : 0.2f * vB;
            exB = __expf(fminf(vB, 60.f));
            if (e16 < cnt) s_w[wid][e16 * 6 + hB] = exB;
        }
        // per-batch head sums via 16-lane group reduction
        float sA = (e16 < cnt) ? exA : 0.f;
        sA += __shfl_xor(sA, 1); sA += __shfl_xor(sA, 2);
        sA += __shfl_xor(sA, 4); sA += __shfl_xor(sA, 8);
        float sB = (lane < 32 && e16 < cnt) ? exB : 0.f;
        sB += __shfl_xor(sB, 1); sB += __shfl_xor(sB, 2);
        sB += __shfl_xor(sB, 4); sB += __shfl_xor(sB, 8);
        if (e16 == 0) {
            s_sum[wid][hA] += sA;                    // lanes 0,16,32,48 -> heads 0-3
            if (lane < 32) s_sum[wid][hB] += sB;     // lanes 0,16     -> heads 4-5
        }
        // wave-coherent LDS (lockstep), no barrier
        int e = 0;
        for (; e + 4 <= cnt; e += 4) {
            int s0 = s_i[wid][e],     s1 = s_i[wid][e + 1];
            int s2 = s_i[wid][e + 2], s3 = s_i[wid][e + 3];
            uint2 d0 = *(const uint2*)(x + (size_t)s0 * 256 + c4);
            uint2 d1 = *(const uint2*)(x + (size_t)s1 * 256 + c4);
            uint2 d2 = *(const uint2*)(x + (size_t)s2 * 256 + c4);
            uint2 d3 = *(const uint2*)(x + (size_t)s3 * 256 + c4);
            float f00 = blo(d0.x), f01 = bhi(d0.x), f02 = blo(d0.y), f03 = bhi(d0.y);
            float f10 = blo(d1.x), f11 = bhi(d1.x), f12 = blo(d1.y), f13 = bhi(d1.y);
            float f20 = blo(d2.x), f21 = bhi(d2.x), f22 = blo(d2.y), f23 = bhi(d2.y);
            float f30 = blo(d3.x), f31 = bhi(d3.x), f32 = blo(d3.y), f33 = bhi(d3.y);
            #pragma unroll
            for (int hh = 0; hh < 6; hh++) {
                float w0 = s_w[wid][e * 6 + hh];
                float w1 = s_w[wid][(e + 1) * 6 + hh];
                float w2 = s_w[wid][(e + 2) * 6 + hh];
                float w3 = s_w[wid][(e + 3) * 6 + hh];
                acc[hh][0] = fmaf(w0, f00, acc[hh][0]);
                acc[hh][1] = fmaf(w0, f01, acc[hh][1]);
                acc[hh][2] = fmaf(w0, f02, acc[hh][2]);
                acc[hh][3] = fmaf(w0, f03, acc[hh][3]);
                acc[hh][0] = fmaf(w1, f10, acc[hh][0]);
                acc[hh][1] = fmaf(w1, f11, acc[hh][1]);
                acc[hh][2] = fmaf(w1, f12, acc[hh][2]);
                acc[hh][3] = fmaf(w1, f13, acc[hh][3]);
                acc[hh][0] = fmaf(w2, f20, acc[hh][0]);
                acc[hh][1] = fmaf(w2, f21, acc[hh][1]);
                acc[hh][2] = fmaf(w2, f22, acc[hh][2]);
                acc[hh][3] = fmaf(w2, f23, acc[hh][3]);
                acc[hh][0] = fmaf(w3, f30, acc[hh][0]);
                acc[hh][1] = fmaf(w3, f31, acc[hh][1]);
                acc[hh][2] = fmaf(w3, f32, acc[hh][2]);
                acc[hh][3] = fmaf(w3, f33, acc[hh][3]);
            }
        }
        for (; e < cnt; e++) {
            int s = s_i[wid][e];
            uint2 d = *(const uint2*)(x + (size_t)s * 256 + c4);
            float v0 = blo(d.x), v1 = bhi(d.x), v2 = blo(d.y), v3 = bhi(d.y);
            #pragma unroll
            for (int hh = 0; hh < 6; hh++) {
                float w = s_w[wid][e * 6 + hh];
                acc[hh][0] = fmaf(w, v0, acc[hh][0]);
                acc[hh][1] = fmaf(w, v1, acc[hh][1]);
                acc[hh][2] = fmaf(w, v2, acc[hh][2]);
                acc[hh][3] = fmaf(w, v3, acc[hh][3]);
            }
        }
    }
    #pragma unroll
    for (int hh = 0; hh < 6; hh++) {
        float inv = 1.f / (6.f * (s_sum[wid][hh] + 1e-16f));
        ushort4 o;
        o.x = f2b(acc[hh][0] * inv);
        o.y = f2b(acc[hh][1] * inv);
        o.z = f2b(acc[hh][2] * inv);
        o.w = f2b(acc[hh][3] * inv);
        *(ushort4*)(S + (size_t)li * 1536 + hh * 256 + c4) = o;
    }
}

// ---------------- host ----------------

extern "C" void kernel_launch(void* const* d_in, const int* in_sizes, int n_in,
                              void* d_out, int out_size, void* d_ws, size_t ws_size,
                              hipStream_t stream) {
    const float* x      = (const float*)d_in[0];
    const int*   src    = (const int*)d_in[1];
    const int*   dst    = (const int*)d_in[2];
    const float* W1     = (const float*)d_in[3];
    const float* a1_src = (const float*)d_in[4];
    const float* a1_dst = (const float*)d_in[5];
    const float* b1     = (const float*)d_in[6];
    const float* W2     = (const float*)d_in[7];
    const float* a2_src = (const float*)d_in[8];
    const float* a2_dst = (const float*)d_in[9];
    const float* b2     = (const float*)d_in[10];
    const float* Wres2  = (const float*)d_in[11];
    const float* W3     = (const float*)d_in[12];
    const float* a3_src = (const float*)d_in[13];
    const float* a3_dst = (const float*)d_in[14];
    const float* b3     = (const float*)d_in[15];
    float* out = (float*)d_out;

    const int N = NODES, E = EDGES;
    const int EN = E + N;
    const int NB = (N + 255) / 256;  // 196
    const int NRT = MPAD / 128;      // 391 row tiles

    char* p = (char*)d_ws;
    auto alloc = [&](size_t bytes) -> char* {
        char* r = p;
        p += (bytes + 511) & ~(size_t)511;
        return r;
    };
    // persistent
    int*   row_ptr = (int*)alloc((size_t)(N + 1) * sizeof(int));
    int*   cursor  = (int*)alloc((size_t)N * sizeof(int));
    int*   deg     = (int*)alloc((size_t)N * sizeof(int));
    int*   bsum    = (int*)alloc(256 * sizeof(int));
    int*   csr_src = (int*)alloc((size_t)EN * sizeof(int));
    float* alA     = (float*)alloc((size_t)N * 8 * sizeof(float));
    float* alB     = (float*)alloc((size_t)N * 8 * sizeof(float));
    float* al3     = (float*)alloc((size_t)N * 12 * sizeof(float));
    float* q1t     = (float*)alloc((size_t)8 * 128 * sizeof(float));
    float* q2t     = (float*)alloc((size_t)8 * 256 * sizeof(float));
    float* cm      = (float*)alloc((size_t)12 * 256 * sizeof(float));
    u16*   WT1     = (u16*)alloc((size_t)256 * 128 * sizeof(u16));
    u16*   WT2     = (u16*)alloc((size_t)512 * 256 * sizeof(u16));
    u16*   W3sT    = (u16*)alloc((size_t)128 * 1536 * sizeof(u16));
    u16*   o2b     = (u16*)alloc((size_t)MPAD * 256 * sizeof(u16));
    // region2 (phase-overlaid)
    const size_t A2B_B  = (size_t)MPAD * 256 * sizeof(u16);
    const size_t F1B_B  = (size_t)N * 256 * sizeof(u16);
    const size_t RESB_B = (size_t)N * 256 * sizeof(u16);
    const size_t S_FULL = (size_t)N * 1536 * sizeof(u16);     // 153.6 MB
    const size_t S_CHNK = (size_t)C0 * 1536 * sizeof(u16);    // 77 MB
    size_t base_need = A2B_B + F1B_B + RESB_B;
    // decide layer-3 path from the REMAINING workspace
    size_t used = (size_t)(p - (char*)d_ws);
    size_t avail = (ws_size > used) ? ws_size - used - 2048 : 0;
    bool fullS = avail >= (S_FULL > base_need ? S_FULL : base_need);
    size_t r2_bytes = base_need;
    size_t s_bytes = fullS ? S_FULL : S_CHNK;
    if (s_bytes > r2_bytes) r2_bytes = s_bytes;
    if (r2_bytes > avail) r2_bytes = avail;   // paranoid clamp (chunked fits by construction)
    char* r2 = alloc(r2_bytes + 1024);
    u16* A2b  = (u16*)r2;                        // layer-1 out bf16 [MPAD,256]
    u16* f1b  = (u16*)(r2 + A2B_B);              // layer feat bf16 [N,256]
    u16* resb = (u16*)(r2 + A2B_B + F1B_B);      // layer-2 residual bf16 [N,256]
    u16* A2a  = (u16*)(r2 + A2B_B + F1B_B);      // x bf16 [MPAD,128] (dead before resb)
    u16* Sb   = (u16*)r2;                        // S bf16 (layer 3; full or chunked)
    (void)n_in; (void)in_sizes; (void)out_size;

    // --- CSR build (deg zeroed by memset; hist counts edges + self-loops) ---
    hipMemsetAsync(deg, 0, (size_t)N * sizeof(int), stream);
    hist_kernel<<<(EN + 255) / 256, 256, 0, stream>>>(dst, deg, E, N);
    deg_bsum_kernel<<<NB, 256, 0, stream>>>(deg, bsum, N);
    bsum_scan_kernel<<<1, 256, 0, stream>>>(bsum, row_ptr, NB, N);
    deg_scan_kernel<<<NB, 256, 0, stream>>>(deg, bsum, row_ptr, cursor, N);
    scatter_kernel<<<(EN + 255) / 256, 256, 0, stream>>>(src, dst, E, N, cursor, csr_src);

    int nwb = (N + 3) / 4;

    // --- all weight prep in one launch ---
    prep_weights<<<(PREP_TOTAL + 255) / 256, 256, 0, stream>>>(
        W1, W2, Wres2, W3, a1_src, a1_dst, a2_src, a2_dst, a3_src, a3_dst,
        WT1, WT2, W3sT, q1t, q2t, cm);

    // --- layer 1: 128 -> 4x64 concat, ELU ---
    convx_al1<<<nwb, 256, 0, stream>>>(x, q1t, A2a, alA, N);
    {
        int nblk = 8 * ((NRT + 7) / 8) * 2;   // XCD-swizzled 1D grid, NT=2
        gemm_mfma_kernel<<<nblk, 256, 0, stream>>>(A2a, WT1, f1b, nullptr,
                                                   N, 128, 256, 9999, 2, NRT);
    }
    // agg + fused layer-2 logits (alB = rounded_out . q2t)
    agg4_fused<8><<<nwb, 256, 0, stream>>>(f1b, alA, row_ptr, csr_src, b1, nullptr,
                                           A2b, q2t, alB, N);

    // --- layer 2: 256 -> 4x64 concat + residual (one 512-wide GEMM), ELU ---
    {
        int nblk = 8 * ((NRT + 7) / 8) * 4;   // NT=4
        gemm_mfma_kernel<<<nblk, 256, 0, stream>>>(A2b, WT2, f1b, resb,
                                                   N, 256, 256, 256, 4, NRT);
    }
    // agg + fused layer-3 logits (al3 = rounded_out . cm)
    agg4_fused<12><<<nwb, 256, 0, stream>>>(f1b, alB, row_ptr, csr_src, b2, resb,
                                            o2b, cm, al3, N);

    // --- layer 3: fused softmax+input-space agg -> skinny GEMM ---
    if (fullS) {
        aggS_fused<<<(N + 3) / 4, 256, 0, stream>>>(o2b, al3, row_ptr, csr_src, Sb, 0, N);
        gemm_skinny64<<<(N + 63) / 64, 256, 0, stream>>>(Sb, W3sT, out, b3, N);
    } else {
        aggS_fused<<<(C0 + 3) / 4, 256, 0, stream>>>(o2b, al3, row_ptr, csr_src, Sb, 0, C0);
        gemm_skinny64<<<(C0 + 63) / 64, 256, 0, stream>>>(Sb, W3sT, out, b3, C0);
        aggS_fused<<<(C1 + 3) / 4, 256, 0, stream>>>(o2b, al3, row_ptr, csr_src, Sb, C0, C1);
        gemm_skinny64<<<(C1 + 63) / 64, 256, 0, stream>>>(Sb, W3sT, out + (size_t)C0 * 121, b3, C1);
    }
}